// Round 9
// baseline (591.016 us; speedup 1.0000x reference)
//
#include <hip/hip_runtime.h>
#include <math.h>

#define G_N 20000
#define NPAD 20032

static __device__ __forceinline__ float gelu_exact(float t) {
    return 0.5f * t * (1.0f + erff(t * 0.70710678118654752440f));
}

// ---------------------------------------------------------------- pre-MLP v3: 64 pts/block, 2-phase LDS (anti-spill)
__global__ void __launch_bounds__(256) k_pre(const float* __restrict__ x,
        const float* __restrict__ coords,
        const float* __restrict__ w1, const float* __restrict__ b1,
        const float* __restrict__ w2, const float* __restrict__ b2,
        float* __restrict__ ut) {
    __shared__ float s_hid[128][64];
    int t = threadIdx.x;
    int p = t & 63;
    int og = __builtin_amdgcn_readfirstlane(t >> 6);   // wave-uniform
    int nb = blockIdx.x * 64;
    int n = nb + p;
    bool valid = n < G_N;
    int nn = valid ? n : 0;
    float in5[5];
    in5[0] = x[nn]; in5[1] = x[G_N + nn]; in5[2] = x[2 * G_N + nn];
    in5[3] = coords[nn]; in5[4] = coords[G_N + nn];
    #pragma unroll 4
    for (int i = 0; i < 32; ++i) {
        int o = og * 32 + i;
        float h = b1[o];
        #pragma unroll
        for (int d = 0; d < 5; ++d) h = fmaf(in5[d], w1[d * 128 + o], h);
        s_hid[o][p] = gelu_exact(h);
    }
    __syncthreads();
    int c0 = og * 16;
    float acc[16];
    const float4* b4 = (const float4*)(b2 + c0);
    float4 bb;
    bb = b4[0]; acc[0]=bb.x; acc[1]=bb.y; acc[2]=bb.z; acc[3]=bb.w;
    bb = b4[1]; acc[4]=bb.x; acc[5]=bb.y; acc[6]=bb.z; acc[7]=bb.w;
    bb = b4[2]; acc[8]=bb.x; acc[9]=bb.y; acc[10]=bb.z; acc[11]=bb.w;
    bb = b4[3]; acc[12]=bb.x; acc[13]=bb.y; acc[14]=bb.z; acc[15]=bb.w;
    #pragma unroll 2
    for (int o = 0; o < 128; ++o) {
        float a = s_hid[o][p];
        const float4* w4 = (const float4*)(w2 + o * 64 + c0);
        #pragma unroll
        for (int q = 0; q < 4; ++q) {
            float4 w = w4[q];
            acc[q*4+0] = fmaf(a, w.x, acc[q*4+0]);
            acc[q*4+1] = fmaf(a, w.y, acc[q*4+1]);
            acc[q*4+2] = fmaf(a, w.z, acc[q*4+2]);
            acc[q*4+3] = fmaf(a, w.w, acc[q*4+3]);
        }
    }
    if (valid) {
        float4* outp = (float4*)(ut + (size_t)n * 64 + c0);
        #pragma unroll
        for (int q = 0; q < 4; ++q)
            outp[q] = make_float4(acc[q*4+0], acc[q*4+1], acc[q*4+2], acc[q*4+3]);
    }
}

// ---------------------------------------------------------------- IPHI: tiled LDS GEMM, 64 pts/block
__shared__ float s_act[128][64];
__shared__ float s_wbuf[32][128];

__device__ __forceinline__ void iphi_gemm(const float* __restrict__ W,
        const float* __restrict__ b, int K, bool dotanh, int t) {
    int po = t & 15, oo = t >> 4;
    int o0 = oo * 8, p0 = po * 4;
    float acc[8][4];
    #pragma unroll
    for (int q = 0; q < 8; ++q)
        #pragma unroll
        for (int j = 0; j < 4; ++j) acc[q][j] = 0.0f;
    for (int kc = 0; kc < K; kc += 32) {
        __syncthreads();
        const float4* src = (const float4*)(W + (size_t)kc * 128);
        float4* dst = (float4*)&s_wbuf[0][0];
        #pragma unroll
        for (int i = 0; i < 4; ++i) dst[i * 256 + t] = src[i * 256 + t];
        __syncthreads();
        #pragma unroll 4
        for (int kk = 0; kk < 32; ++kk) {
            float4 a  = *(const float4*)&s_act[kc + kk][p0];
            float4 w0 = *(const float4*)&s_wbuf[kk][o0];
            float4 w1 = *(const float4*)&s_wbuf[kk][o0 + 4];
            float wv[8] = {w0.x, w0.y, w0.z, w0.w, w1.x, w1.y, w1.z, w1.w};
            float av[4] = {a.x, a.y, a.z, a.w};
            #pragma unroll
            for (int q = 0; q < 8; ++q)
                #pragma unroll
                for (int j = 0; j < 4; ++j)
                    acc[q][j] = fmaf(wv[q], av[j], acc[q][j]);
        }
    }
    __syncthreads();
    #pragma unroll
    for (int q = 0; q < 8; ++q) {
        float bo = b[o0 + q];
        float r0 = acc[q][0] + bo, r1 = acc[q][1] + bo;
        float r2 = acc[q][2] + bo, r3 = acc[q][3] + bo;
        if (dotanh) { r0 = tanhf(r0); r1 = tanhf(r1); r2 = tanhf(r2); r3 = tanhf(r3); }
        *(float4*)&s_act[o0 + q][p0] = make_float4(r0, r1, r2, r3);
    }
}

__global__ void __launch_bounds__(256) k_iphi(const float* __restrict__ coords,
        const float* __restrict__ fc0w, const float* __restrict__ fc0b,
        const float* __restrict__ fncw, const float* __restrict__ fncb,
        const float* __restrict__ fc1w, const float* __restrict__ fc1b,
        const float* __restrict__ fc2w, const float* __restrict__ fc2b,
        const float* __restrict__ fc3w, const float* __restrict__ fc3b,
        const float* __restrict__ fc4w, const float* __restrict__ fc4b,
        float* __restrict__ e1t, float* __restrict__ e2t) {
    __shared__ float xdl[4][64];
    __shared__ float ccs[2][64];
    __shared__ float xout[2][64];
    int t = threadIdx.x;
    int nb = blockIdx.x * 64;
    if (t < 64) {
        int n = nb + t; bool v = n < G_N;
        float c0 = v ? coords[n] : 0.5f;
        float c1 = v ? coords[G_N + n] : 0.5f;
        ccs[0][t] = c0; ccs[1][t] = c1;
        float xc0 = c0 - 1e-4f, xc1 = c1 - 1e-4f;
        xdl[0][t] = c0; xdl[1][t] = c1;
        xdl[2][t] = atan2f(xc1, xc0);
        xdl[3][t] = sqrtf(fmaf(xc0, xc0, xc1 * xc1));
    }
    __syncthreads();
    const float PI_F = 3.14159274101257324f;
    #pragma unroll
    for (int i = 0; i < 24; ++i) {
        int idx = i * 256 + t;
        int f = idx >> 6, p = idx & 63;
        float v;
        if (f < 32) {
            v = fc0b[f];
            #pragma unroll
            for (int d = 0; d < 4; ++d) v = fmaf(xdl[d][p], fc0w[d * 32 + f], v);
        } else {
            int ff = f - 32;
            int d = (ff >> 3) & 3, j = ff & 7;
            float arg = xdl[d][p] * (PI_F * (float)(1 << j));
            v = (f < 64) ? sinf(arg) : cosf(arg);
        }
        s_act[f][p] = v;
    }
    iphi_gemm(fncw, fncb,  96, false, t);
    iphi_gemm(fc1w, fc1b, 128, true,  t);
    iphi_gemm(fc2w, fc2b, 128, true,  t);
    iphi_gemm(fc3w, fc3b, 128, true,  t);
    __syncthreads();
    if (t < 128) {
        int o = t >> 6, p = t & 63;
        float a = fc4b[o];
        for (int k = 0; k < 128; ++k) a = fmaf(s_act[k][p], fc4w[k * 2 + o], a);
        float c = ccs[o][p];
        xout[o][p] = fmaf(c, a, c);
    }
    __syncthreads();
    int p = t & 63, og = t >> 6;
    int n = nb + p;
    if (n >= G_N) return;
    float xa = xout[0][p], xb = xout[1][p];
    const float TWO_PI = 6.28318548202514648f;
    float2* E1 = (float2*)e1t;
    float2* E2 = (float2*)e2t;
    if (og == 0) {
        for (int k = 0; k < 12; ++k) {
            float s, c; sincosf(TWO_PI * (xa * (float)k), &s, &c);
            E1[(size_t)k * NPAD + n] = make_float2(c, s);
        }
    } else if (og == 1) {
        for (int k = 12; k < 24; ++k) {
            float s, c; sincosf(TWO_PI * (xa * (float)(k - 24)), &s, &c);
            E1[(size_t)k * NPAD + n] = make_float2(c, s);
        }
    } else if (og == 2) {
        for (int k = 0; k < 12; ++k) {
            float s, c; sincosf(TWO_PI * (xb * (float)k), &s, &c);
            E2[(size_t)k * NPAD + n] = make_float2(c, s);
        }
    } else {
        for (int k = 12; k < 23; ++k) {
            float s, c; sincosf(TWO_PI * (xb * (float)(k - 23)), &s, &c);
            E2[(size_t)k * NPAD + n] = make_float2(c, s);
        }
    }
}

// ---------------------------------------------------------------- project_in: chunk-major partials, c-split x8
__global__ void __launch_bounds__(320) k_proj_in(const float* __restrict__ ut,
        const float* __restrict__ e1t, const float* __restrict__ e2t,
        float* __restrict__ partial) {
    int t = threadIdx.x;
    if (t >= 288) return;
    int chunk = blockIdx.x;               // 0..127
    int c0 = blockIdx.y * 8;              // 8 channels per block
    int xm = t / 12, ky = t % 12;
    const float2* E1 = (const float2*)e1t + (size_t)xm * NPAD;
    const float2* E2 = (const float2*)e2t + (size_t)ky * NPAD;
    float accr[8], acci[8];
    #pragma unroll
    for (int q = 0; q < 8; ++q) { accr[q] = 0.f; acci[q] = 0.f; }
    int n0 = chunk * 157;
    int n1 = n0 + 157; if (n1 > G_N) n1 = G_N;
    for (int n = n0; n < n1; ++n) {
        float2 e1 = E1[n];
        float2 e2 = E2[n];
        float br  =  e1.x * e2.x - e1.y * e2.y;
        float nbi = -(e1.x * e2.y + e1.y * e2.x);
        const float4* uv = (const float4*)(ut + (size_t)n * 64 + c0);
        #pragma unroll
        for (int q = 0; q < 2; ++q) {
            float4 u = uv[q];
            accr[q*4+0] = fmaf(u.x, br, accr[q*4+0]); acci[q*4+0] = fmaf(u.x, nbi, acci[q*4+0]);
            accr[q*4+1] = fmaf(u.y, br, accr[q*4+1]); acci[q*4+1] = fmaf(u.y, nbi, acci[q*4+1]);
            accr[q*4+2] = fmaf(u.z, br, accr[q*4+2]); acci[q*4+2] = fmaf(u.z, nbi, acci[q*4+2]);
            accr[q*4+3] = fmaf(u.w, br, accr[q*4+3]); acci[q*4+3] = fmaf(u.w, nbi, acci[q*4+3]);
        }
    }
    float2* pb = (float2*)(partial + (size_t)chunk * 36864);
    #pragma unroll
    for (int q = 0; q < 8; ++q)
        pb[(size_t)(c0 + q) * 288 + t] = make_float2(accr[q], acci[q]);
}

// ---------------------------------------------------------------- project_in stage 2: 128-chunk sum
__global__ void __launch_bounds__(256) k_reduce(const float* __restrict__ partial,
        float* __restrict__ uft) {
    int o = blockIdx.x * 256 + threadIdx.x;   // 0..36863
    float s = 0.f;
    #pragma unroll 8
    for (int ch = 0; ch < 128; ++ch)
        s += partial[(size_t)ch * 36864 + o];
    uft[o] = s;
}

// ---------------------------------------------------------------- channel mix (pin) + 1/9216 fold
__global__ void __launch_bounds__(320) k_mix_in(const float* __restrict__ uft,
        const float* __restrict__ w1re, const float* __restrict__ w1im,
        const float* __restrict__ w2re, const float* __restrict__ w2im,
        float* __restrict__ fmix) {
    int t = threadIdx.x; if (t >= 288) return;
    int o = blockIdx.x;
    int xm = t / 12, ky = t % 12;
    const float *wre, *wim; int xl;
    if (xm < 12) { wre = w1re; wim = w1im; xl = xm; }
    else         { wre = w2re; wim = w2im; xl = xm - 12; }
    float fr = 0.f, fi = 0.f;
    for (int i = 0; i < 64; ++i) {
        float2 u = *(const float2*)(uft + ((size_t)i * 288 + t) * 2);
        int wi_ = ((i * 64 + o) * 12 + xl) * 12 + ky;
        float wr = wre[wi_], wq = wim[wi_];
        fr = fmaf(u.x, wr, fr); fr = fmaf(-u.y, wq, fr);
        fi = fmaf(u.x, wq, fi); fi = fmaf(u.y, wr, fi);
    }
    const float sc = 1.0f / 9216.0f;
    fmix[((size_t)o * 288 + t) * 2]     = fr * sc;
    fmix[((size_t)o * 288 + t) * 2 + 1] = fi * sc;
}

// ---------------------------------------------------------------- sparse irfft2 -> u (single buffer)
__global__ void __launch_bounds__(256) k_igrid(const float* __restrict__ fmix,
        float* __restrict__ u) {
    __shared__ float2 tw[96];
    __shared__ float2 Fs[288];
    __shared__ float2 T[12][24];
    int t = threadIdx.x, c = blockIdx.x;
    int ac0 = blockIdx.y * 24;
    if (t < 96) {
        float s, co; sincosf(6.28318548202514648f * (float)t / 96.0f, &s, &co);
        tw[t] = make_float2(co, s);
    }
    for (int i = t; i < 288; i += 256)
        Fs[i] = *(const float2*)(fmix + ((size_t)c * 288 + i) * 2);
    __syncthreads();
    for (int i = t; i < 288; i += 256) {
        int kyy = i / 24, a = ac0 + (i % 24);
        float tr = 0.f, ti = 0.f;
        int m = 0;
        #pragma unroll
        for (int xx = 0; xx < 12; ++xx) {
            float2 w = tw[m]; float2 f = Fs[xx * 12 + kyy];
            tr += f.x * w.x - f.y * w.y;
            ti += f.x * w.y + f.y * w.x;
            m += a; if (m >= 96) m -= 96;
        }
        m = (84 * a) % 96;
        #pragma unroll
        for (int xx = 12; xx < 24; ++xx) {
            float2 w = tw[m]; float2 f = Fs[xx * 12 + kyy];
            tr += f.x * w.x - f.y * w.y;
            ti += f.x * w.y + f.y * w.x;
            m += a; if (m >= 96) m -= 96;
        }
        T[kyy][i % 24] = make_float2(tr, ti);
    }
    __syncthreads();
    for (int i = t; i < 2304; i += 256) {
        int al = i / 96, j = i % 96;
        float s = T[0][al].x;
        int m = j;
        #pragma unroll
        for (int kyy = 1; kyy < 12; ++kyy) {
            float2 w = tw[m]; float2 tt = T[kyy][al];
            s += 2.0f * (tt.x * w.x - tt.y * w.y);
            m += j; if (m >= 96) m -= 96;
        }
        u[(size_t)c * 9216 + (ac0 + al) * 96 + j] = s;
    }
}

// ---------------------------------------------------------------- FFNO stage A: truncated DFT both dims
__global__ void __launch_bounds__(256) kf_dft(const float* __restrict__ u,
        float* __restrict__ fy, float* __restrict__ fx) {
    __shared__ float us[2400];
    __shared__ float2 tw[96];
    int t = threadIdx.x;
    int c = blockIdx.x, q4 = blockIdx.y, brn = blockIdx.z;
    if (t < 96) {
        float s, co; sincosf(6.28318548202514648f * (float)t / 96.0f, &s, &co);
        tw[t] = make_float2(co, s);
    }
    const float* uc = u + (size_t)c * 9216;
    if (brn == 0) {
        for (int i = t; i < 2304; i += 256) {
            int row = i / 96, col = i % 96;
            us[row * 97 + col] = uc[(q4 * 24 + row) * 96 + col];
        }
    } else {
        for (int i = t; i < 2304; i += 256) {
            int row = i / 24, col = i % 24;
            us[row * 24 + col] = uc[row * 96 + q4 * 24 + col];
        }
    }
    __syncthreads();
    float2* F = (float2*)((brn == 0) ? fy : fx) + (size_t)c * 1152;
    for (int i = t; i < 288; i += 256) {
        int k = i / 24, sl = i % 24;
        int s = q4 * 24 + sl;
        float fr = 0.f, fi = 0.f;
        int m = 0;
        if (brn == 0) {
            for (int r = 0; r < 96; ++r) {
                float uv = us[sl * 97 + r];
                float2 w = tw[m];
                fr = fmaf(uv, w.x, fr); fi = fmaf(-uv, w.y, fi);
                m += k; if (m >= 96) m -= 96;
            }
        } else {
            for (int r = 0; r < 96; ++r) {
                float uv = us[r * 24 + sl];
                float2 w = tw[m];
                fr = fmaf(uv, w.x, fr); fi = fmaf(-uv, w.y, fi);
                m += k; if (m >= 96) m -= 96;
            }
        }
        F[k * 96 + s] = make_float2(fr, fi);
    }
}

// ---------------------------------------------------------------- FFNO stage B: channel mix per mode (split x3)
__global__ void __launch_bounds__(384) kf_mix(const float* __restrict__ fy,
        const float* __restrict__ fx,
        const float* __restrict__ wyre, const float* __restrict__ wyim,
        const float* __restrict__ wxre, const float* __restrict__ wxim,
        float* __restrict__ gy, float* __restrict__ gx) {
    int t = threadIdx.x;
    int o = blockIdx.x, brn = blockIdx.y;
    int idx = blockIdx.z * 384 + t;
    const float2* F = (const float2*)((brn == 0) ? fy : fx);
    const float* wre = (brn == 0) ? wyre : wxre;
    const float* wim = (brn == 0) ? wyim : wxim;
    float2* G = (float2*)((brn == 0) ? gy : gx) + (size_t)o * 1152;
    int k = idx / 96;
    float gr = 0.f, gi = 0.f;
    #pragma unroll 4
    for (int i = 0; i < 64; ++i) {
        float2 f = F[(size_t)i * 1152 + idx];
        int wi_ = (i * 64 + o) * 12 + k;
        float wr = wre[wi_], wq = wim[wi_];
        gr += f.x * wr - f.y * wq;
        gi += f.x * wq + f.y * wr;
    }
    G[idx] = make_float2(gr, gi);
}

// ---------------------------------------------------------------- FFNO stage C: inverse DFTs + residual, in place
__global__ void __launch_bounds__(256) kf_inv(const float* __restrict__ gy,
        const float* __restrict__ gx, float* __restrict__ u) {
    __shared__ float2 sgx[12][96];
    __shared__ float2 sgy[12][24];
    __shared__ float2 tw[96];
    int t = threadIdx.x;
    int c = blockIdx.x, aq = blockIdx.y;
    if (t < 96) {
        float s, co; sincosf(6.28318548202514648f * (float)t / 96.0f, &s, &co);
        tw[t] = make_float2(co, s);
    }
    const float2* Gy = (const float2*)gy + (size_t)c * 1152;
    const float2* Gx = (const float2*)gx + (size_t)c * 1152;
    for (int i = t; i < 1152; i += 256) sgx[i / 96][i % 96] = Gx[i];
    for (int i = t; i < 288; i += 256)
        sgy[i / 24][i % 24] = Gy[(i / 24) * 96 + aq * 24 + (i % 24)];
    __syncthreads();
    const float inv = 1.0f / 96.0f;
    float* uc = u + (size_t)c * 9216;
    for (int idx = t; idx < 2304; idx += 256) {
        int al = idx / 96, j = idx % 96;
        int a = aq * 24 + al;
        float sY = sgy[0][al].x;
        int m = j;
        #pragma unroll
        for (int k = 1; k < 12; ++k) {
            float2 g = sgy[k][al]; float2 w = tw[m];
            sY += 2.0f * (g.x * w.x - g.y * w.y);
            m += j; if (m >= 96) m -= 96;
        }
        float sX = sgx[0][j].x;
        m = a;
        #pragma unroll
        for (int k = 1; k < 12; ++k) {
            float2 g = sgx[k][j]; float2 w = tw[m];
            sX += 2.0f * (g.x * w.x - g.y * w.y);
            m += a; if (m >= 96) m -= 96;
        }
        uc[a * 96 + j] += (sY + sX) * inv;
    }
}

// ---------------------------------------------------------------- forward truncated rfft2 -> uftO
__global__ void __launch_bounds__(512) k_ogrid(const float* __restrict__ u,
        float* __restrict__ uftO) {
    __shared__ float ug[96][97];
    __shared__ float2 P[12][97];
    __shared__ float2 tw[96];
    int t = threadIdx.x, c = blockIdx.x;
    if (t < 96) {
        float s, co; sincosf(6.28318548202514648f * (float)t / 96.0f, &s, &co);
        tw[t] = make_float2(co, s);
    }
    for (int q = 0; q < 18; ++q) {
        int idx = q * 512 + t;
        ug[idx / 96][idx % 96] = u[(size_t)c * 9216 + idx];
    }
    __syncthreads();
    for (int q = 0; q < 3; ++q) {
        int idx = q * 512 + t;
        if (idx < 1152) {
            int ky = idx / 96, a = idx % 96;
            float fr = 0.f, fi = 0.f;
            int m = 0;
            for (int j = 0; j < 96; ++j) {
                float uv = ug[a][j];
                float2 w = tw[m];
                fr = fmaf(uv, w.x, fr); fi = fmaf(-uv, w.y, fi);
                m += ky; if (m >= 96) m -= 96;
            }
            P[ky][a] = make_float2(fr, fi);
        }
    }
    __syncthreads();
    if (t < 288) {
        int x = t / 12, ky = t % 12;
        int k1m = (x < 12) ? x : (x + 72);
        float gr = 0.f, gi = 0.f;
        int m = 0;
        for (int a = 0; a < 96; ++a) {
            float2 p = P[ky][a];
            float2 w = tw[m];
            gr += p.x * w.x + p.y * w.y;
            gi += p.y * w.x - p.x * w.y;
            m += k1m; if (m >= 96) m -= 96;
        }
        uftO[((size_t)c * 288 + t) * 2]     = gr;
        uftO[((size_t)c * 288 + t) * 2 + 1] = gi;
    }
}

// ---------------------------------------------------------------- channel mix (pout) + Hermitian completion
__global__ void __launch_bounds__(320) k_mix_out(const float* __restrict__ uftO,
        const float* __restrict__ w1re, const float* __restrict__ w1im,
        const float* __restrict__ w2re, const float* __restrict__ w2im,
        float* __restrict__ ffull) {
    int t = threadIdx.x; if (t >= 288) return;
    int o = blockIdx.x;
    int xm = t / 12, ky = t % 12;
    const float *wre, *wim; int xl;
    if (xm < 12) { wre = w1re; wim = w1im; xl = xm; }
    else         { wre = w2re; wim = w2im; xl = xm - 12; }
    float fr = 0.f, fi = 0.f;
    for (int i = 0; i < 64; ++i) {
        float2 u = *(const float2*)(uftO + ((size_t)i * 288 + t) * 2);
        int wi_ = ((i * 64 + o) * 12 + xl) * 12 + ky;
        float wr = wre[wi_], wq = wim[wi_];
        fr = fmaf(u.x, wr, fr); fr = fmaf(-u.y, wq, fr);
        fi = fmaf(u.x, wq, fi); fi = fmaf(u.y, wr, fi);
    }
    int M = xm * 23 + ky;
    ffull[((size_t)M * 64 + o) * 2]     = fr;
    ffull[((size_t)M * 64 + o) * 2 + 1] = fi;
    if (ky > 0) {
        int Mc = (23 - xm) * 23 + (23 - ky);
        ffull[((size_t)Mc * 64 + o) * 2]     = fr;
        ffull[((size_t)Mc * 64 + o) * 2 + 1] = -fi;
    }
}

// ---------------------------------------------------------------- project_out v5: e1 reg-cache, c-split x8, mode-split x2
__global__ void __launch_bounds__(256, 4) k_proj_out(const float* __restrict__ ffull,
        const float* __restrict__ e1t, const float* __restrict__ e2t,
        float* __restrict__ uout) {
    int n = blockIdx.x * 256 + threadIdx.x;
    if (n >= G_N) return;
    int c0 = blockIdx.y * 8;
    int x0 = blockIdx.z * 12;
    const float2* E1 = (const float2*)e1t;
    const float2* E2 = (const float2*)e2t;
    float2 e1c[12];
    #pragma unroll
    for (int xi = 0; xi < 12; ++xi)
        e1c[xi] = E1[(size_t)(x0 + xi) * NPAD + n];
    float acc[8];
    #pragma unroll
    for (int q = 0; q < 8; ++q) acc[q] = 0.f;
    for (int y = 0; y < 23; ++y) {
        float2 e2 = E2[(size_t)y * NPAD + n];
        #pragma unroll
        for (int xi = 0; xi < 12; ++xi) {
            float2 e1 = e1c[xi];
            float br  =  e1.x * e2.x - e1.y * e2.y;
            float nbi = -(e1.x * e2.y + e1.y * e2.x);
            const float4* F = (const float4*)(ffull + ((size_t)((x0 + xi) * 23 + y) * 64 + c0) * 2);
            #pragma unroll
            for (int q = 0; q < 4; ++q) {
                float4 f = F[q];
                acc[q*2+0] = fmaf(f.x, br, acc[q*2+0]);
                acc[q*2+0] = fmaf(f.y, nbi, acc[q*2+0]);
                acc[q*2+1] = fmaf(f.z, br, acc[q*2+1]);
                acc[q*2+1] = fmaf(f.w, nbi, acc[q*2+1]);
            }
        }
    }
    float* ub = uout + (size_t)blockIdx.z * 1282048;
    #pragma unroll
    for (int q = 0; q < 8; ++q)
        ub[(size_t)(c0 + q) * NPAD + n] = acc[q];
}

// ---------------------------------------------------------------- head MLP v2: 64 pts/block, 2-phase LDS (anti-spill)
__global__ void __launch_bounds__(256) k_head(const float* __restrict__ uout,
        const float* __restrict__ w1, const float* __restrict__ b1,
        const float* __restrict__ w2, const float* __restrict__ b2,
        float* __restrict__ out) {
    __shared__ float us[64][64];
    __shared__ float s_g[64][64];
    int t = threadIdx.x;
    int p = t & 63;
    int og = __builtin_amdgcn_readfirstlane(t >> 6);
    int nb = blockIdx.x * 64;
    for (int idx = t; idx < 4096; idx += 256) {
        int c = idx >> 6, pp = idx & 63;
        int n = nb + pp;
        int nn = (n < G_N) ? n : 0;
        us[c][pp] = uout[(size_t)c * NPAD + nn] + uout[1282048 + (size_t)c * NPAD + nn];
    }
    __syncthreads();
    #pragma unroll 2
    for (int i = 0; i < 16; ++i) {
        int o = og * 16 + i;
        float h = b1[o];
        for (int c = 0; c < 64; ++c) h = fmaf(us[c][p], w1[c * 64 + o], h);
        s_g[o][p] = gelu_exact(h);
    }
    __syncthreads();
    if (t < 192) {
        int oi = t >> 6;
        float v = b2[oi];
        for (int k = 0; k < 64; ++k) v = fmaf(s_g[k][p], w2[k * 3 + oi], v);
        int n = nb + p;
        if (n < G_N) out[(size_t)oi * G_N + n] = v;
    }
}

// ================================================================ launch
extern "C" void kernel_launch(void* const* d_in, const int* in_sizes, int n_in,
                              void* d_out, int out_size, void* d_ws, size_t ws_size,
                              hipStream_t stream) {
    const float* x        = (const float*)d_in[0];
    const float* coords   = (const float*)d_in[1];
    const float* pre_w1   = (const float*)d_in[2];
    const float* pre_b1   = (const float*)d_in[3];
    const float* pre_w2   = (const float*)d_in[4];
    const float* pre_b2   = (const float*)d_in[5];
    const float* pin_w1_re  = (const float*)d_in[6];
    const float* pin_w1_im  = (const float*)d_in[7];
    const float* pin_w2_re  = (const float*)d_in[8];
    const float* pin_w2_im  = (const float*)d_in[9];
    const float* pout_w1_re = (const float*)d_in[10];
    const float* pout_w1_im = (const float*)d_in[11];
    const float* pout_w2_re = (const float*)d_in[12];
    const float* pout_w2_im = (const float*)d_in[13];
    const float* ifc0w = (const float*)d_in[14];
    const float* ifc0b = (const float*)d_in[15];
    const float* ifncw = (const float*)d_in[16];
    const float* ifncb = (const float*)d_in[17];
    const float* ifc1w = (const float*)d_in[18];
    const float* ifc1b = (const float*)d_in[19];
    const float* ifc2w = (const float*)d_in[20];
    const float* ifc2b = (const float*)d_in[21];
    const float* ifc3w = (const float*)d_in[22];
    const float* ifc3b = (const float*)d_in[23];
    const float* ifc4w = (const float*)d_in[24];
    const float* ifc4b = (const float*)d_in[25];
    const float* wx_re = (const float*)d_in[26];
    const float* wx_im = (const float*)d_in[27];
    const float* wy_re = (const float*)d_in[28];
    const float* wy_im = (const float*)d_in[29];
    const float* hw1 = (const float*)d_in[30];
    const float* hb1 = (const float*)d_in[31];
    const float* hw2 = (const float*)d_in[32];
    const float* hb2 = (const float*)d_in[33];
    float* out = (float*)d_out;
    float* ws  = (float*)d_ws;

    float* ut      = ws + 0;          // [NPAD][64]
    float* ffull   = ws + 0;          // [552][64][2] (alias after ut dead)
    float* e1t     = ws + 1282048;    // [24][NPAD][2]
    float* e2t     = ws + 2243584;    // [23][NPAD][2]
    float* uft     = ws + 3165056;    // [64][288][2]  (later uftO)
    float* fmix    = ws + 3201920;    // [64][288][2]
    float* u       = ws + 3238784;    // [64][96][96]
    float* fy      = ws + 3828608;    // [64][12][96][2]
    float* fx      = ws + 3976064;
    float* gy      = ws + 4123520;
    float* gx      = ws + 4270976;
    float* partial = ws + 3238784;    // [128][36864] floats (alias, dead before u written)
    float* uout    = ws + 3238784;    // 2 x [64][NPAD] (alias after ogrid)

    k_pre<<<dim3(313), dim3(256), 0, stream>>>(x, coords, pre_w1, pre_b1, pre_w2, pre_b2, ut);
    k_iphi<<<dim3(313), dim3(256), 0, stream>>>(coords, ifc0w, ifc0b, ifncw, ifncb,
            ifc1w, ifc1b, ifc2w, ifc2b, ifc3w, ifc3b, ifc4w, ifc4b, e1t, e2t);
    k_proj_in<<<dim3(128, 8), dim3(320), 0, stream>>>(ut, e1t, e2t, partial);
    k_reduce<<<dim3(144), dim3(256), 0, stream>>>(partial, uft);
    k_mix_in<<<dim3(64), dim3(320), 0, stream>>>(uft, pin_w1_re, pin_w1_im, pin_w2_re, pin_w2_im, fmix);
    k_igrid<<<dim3(64, 4), dim3(256), 0, stream>>>(fmix, u);
    for (int L = 0; L < 4; ++L) {
        kf_dft<<<dim3(64, 4, 2), dim3(256), 0, stream>>>(u, fy, fx);
        kf_mix<<<dim3(64, 2, 3), dim3(384), 0, stream>>>(fy, fx,
                wy_re + (size_t)L * 49152, wy_im + (size_t)L * 49152,
                wx_re + (size_t)L * 49152, wx_im + (size_t)L * 49152, gy, gx);
        kf_inv<<<dim3(64, 4), dim3(256), 0, stream>>>(gy, gx, u);
    }
    k_ogrid<<<dim3(64), dim3(512), 0, stream>>>(u, uft /*as uftO*/);
    k_mix_out<<<dim3(64), dim3(320), 0, stream>>>(uft, pout_w1_re, pout_w1_im,
            pout_w2_re, pout_w2_im, ffull);
    k_proj_out<<<dim3(79, 8, 2), dim3(256), 0, stream>>>(ffull, e1t, e2t, uout);
    k_head<<<dim3(313), dim3(256), 0, stream>>>(uout, hw1, hb1, hw2, hb2, out);
}

// Round 10
// 544.357 us; speedup vs baseline: 1.0857x; 1.0857x over previous
//
#include <hip/hip_runtime.h>
#include <math.h>

#define G_N 20000
#define NPAD 20032

static __device__ __forceinline__ float gelu_exact(float t) {
    return 0.5f * t * (1.0f + erff(t * 0.70710678118654752440f));
}

// ---------------------------------------------------------------- pre-MLP v3: 64 pts/block, 2-phase LDS (anti-spill)
__global__ void __launch_bounds__(256) k_pre(const float* __restrict__ x,
        const float* __restrict__ coords,
        const float* __restrict__ w1, const float* __restrict__ b1,
        const float* __restrict__ w2, const float* __restrict__ b2,
        float* __restrict__ ut) {
    __shared__ float s_hid[128][64];
    int t = threadIdx.x;
    int p = t & 63;
    int og = __builtin_amdgcn_readfirstlane(t >> 6);   // wave-uniform
    int nb = blockIdx.x * 64;
    int n = nb + p;
    bool valid = n < G_N;
    int nn = valid ? n : 0;
    float in5[5];
    in5[0] = x[nn]; in5[1] = x[G_N + nn]; in5[2] = x[2 * G_N + nn];
    in5[3] = coords[nn]; in5[4] = coords[G_N + nn];
    #pragma unroll 4
    for (int i = 0; i < 32; ++i) {
        int o = og * 32 + i;
        float h = b1[o];
        #pragma unroll
        for (int d = 0; d < 5; ++d) h = fmaf(in5[d], w1[d * 128 + o], h);
        s_hid[o][p] = gelu_exact(h);
    }
    __syncthreads();
    int c0 = og * 16;
    float acc[16];
    const float4* b4 = (const float4*)(b2 + c0);
    float4 bb;
    bb = b4[0]; acc[0]=bb.x; acc[1]=bb.y; acc[2]=bb.z; acc[3]=bb.w;
    bb = b4[1]; acc[4]=bb.x; acc[5]=bb.y; acc[6]=bb.z; acc[7]=bb.w;
    bb = b4[2]; acc[8]=bb.x; acc[9]=bb.y; acc[10]=bb.z; acc[11]=bb.w;
    bb = b4[3]; acc[12]=bb.x; acc[13]=bb.y; acc[14]=bb.z; acc[15]=bb.w;
    #pragma unroll 2
    for (int o = 0; o < 128; ++o) {
        float a = s_hid[o][p];
        const float4* w4 = (const float4*)(w2 + o * 64 + c0);
        #pragma unroll
        for (int q = 0; q < 4; ++q) {
            float4 w = w4[q];
            acc[q*4+0] = fmaf(a, w.x, acc[q*4+0]);
            acc[q*4+1] = fmaf(a, w.y, acc[q*4+1]);
            acc[q*4+2] = fmaf(a, w.z, acc[q*4+2]);
            acc[q*4+3] = fmaf(a, w.w, acc[q*4+3]);
        }
    }
    if (valid) {
        float4* outp = (float4*)(ut + (size_t)n * 64 + c0);
        #pragma unroll
        for (int q = 0; q < 4; ++q)
            outp[q] = make_float4(acc[q*4+0], acc[q*4+1], acc[q*4+2], acc[q*4+3]);
    }
}

// ---------------------------------------------------------------- IPHI: tiled LDS GEMM, 64 pts/block
__shared__ float s_act[128][64];
__shared__ float s_wbuf[32][128];

__device__ __forceinline__ void iphi_gemm(const float* __restrict__ W,
        const float* __restrict__ b, int K, bool dotanh, int t) {
    int po = t & 15, oo = t >> 4;
    int o0 = oo * 8, p0 = po * 4;
    float acc[8][4];
    #pragma unroll
    for (int q = 0; q < 8; ++q)
        #pragma unroll
        for (int j = 0; j < 4; ++j) acc[q][j] = 0.0f;
    for (int kc = 0; kc < K; kc += 32) {
        __syncthreads();
        const float4* src = (const float4*)(W + (size_t)kc * 128);
        float4* dst = (float4*)&s_wbuf[0][0];
        #pragma unroll
        for (int i = 0; i < 4; ++i) dst[i * 256 + t] = src[i * 256 + t];
        __syncthreads();
        #pragma unroll 4
        for (int kk = 0; kk < 32; ++kk) {
            float4 a  = *(const float4*)&s_act[kc + kk][p0];
            float4 w0 = *(const float4*)&s_wbuf[kk][o0];
            float4 w1 = *(const float4*)&s_wbuf[kk][o0 + 4];
            float wv[8] = {w0.x, w0.y, w0.z, w0.w, w1.x, w1.y, w1.z, w1.w};
            float av[4] = {a.x, a.y, a.z, a.w};
            #pragma unroll
            for (int q = 0; q < 8; ++q)
                #pragma unroll
                for (int j = 0; j < 4; ++j)
                    acc[q][j] = fmaf(wv[q], av[j], acc[q][j]);
        }
    }
    __syncthreads();
    #pragma unroll
    for (int q = 0; q < 8; ++q) {
        float bo = b[o0 + q];
        float r0 = acc[q][0] + bo, r1 = acc[q][1] + bo;
        float r2 = acc[q][2] + bo, r3 = acc[q][3] + bo;
        if (dotanh) { r0 = tanhf(r0); r1 = tanhf(r1); r2 = tanhf(r2); r3 = tanhf(r3); }
        *(float4*)&s_act[o0 + q][p0] = make_float4(r0, r1, r2, r3);
    }
}

__global__ void __launch_bounds__(256) k_iphi(const float* __restrict__ coords,
        const float* __restrict__ fc0w, const float* __restrict__ fc0b,
        const float* __restrict__ fncw, const float* __restrict__ fncb,
        const float* __restrict__ fc1w, const float* __restrict__ fc1b,
        const float* __restrict__ fc2w, const float* __restrict__ fc2b,
        const float* __restrict__ fc3w, const float* __restrict__ fc3b,
        const float* __restrict__ fc4w, const float* __restrict__ fc4b,
        float* __restrict__ e1t, float* __restrict__ e2t) {
    __shared__ float xdl[4][64];
    __shared__ float ccs[2][64];
    __shared__ float xout[2][64];
    int t = threadIdx.x;
    int nb = blockIdx.x * 64;
    if (t < 64) {
        int n = nb + t; bool v = n < G_N;
        float c0 = v ? coords[n] : 0.5f;
        float c1 = v ? coords[G_N + n] : 0.5f;
        ccs[0][t] = c0; ccs[1][t] = c1;
        float xc0 = c0 - 1e-4f, xc1 = c1 - 1e-4f;
        xdl[0][t] = c0; xdl[1][t] = c1;
        xdl[2][t] = atan2f(xc1, xc0);
        xdl[3][t] = sqrtf(fmaf(xc0, xc0, xc1 * xc1));
    }
    __syncthreads();
    const float PI_F = 3.14159274101257324f;
    #pragma unroll
    for (int i = 0; i < 24; ++i) {
        int idx = i * 256 + t;
        int f = idx >> 6, p = idx & 63;
        float v;
        if (f < 32) {
            v = fc0b[f];
            #pragma unroll
            for (int d = 0; d < 4; ++d) v = fmaf(xdl[d][p], fc0w[d * 32 + f], v);
        } else {
            int ff = f - 32;
            int d = (ff >> 3) & 3, j = ff & 7;
            float arg = xdl[d][p] * (PI_F * (float)(1 << j));
            v = (f < 64) ? sinf(arg) : cosf(arg);
        }
        s_act[f][p] = v;
    }
    iphi_gemm(fncw, fncb,  96, false, t);
    iphi_gemm(fc1w, fc1b, 128, true,  t);
    iphi_gemm(fc2w, fc2b, 128, true,  t);
    iphi_gemm(fc3w, fc3b, 128, true,  t);
    __syncthreads();
    if (t < 128) {
        int o = t >> 6, p = t & 63;
        float a = fc4b[o];
        for (int k = 0; k < 128; ++k) a = fmaf(s_act[k][p], fc4w[k * 2 + o], a);
        float c = ccs[o][p];
        xout[o][p] = fmaf(c, a, c);
    }
    __syncthreads();
    int p = t & 63, og = t >> 6;
    int n = nb + p;
    if (n >= G_N) return;
    float xa = xout[0][p], xb = xout[1][p];
    const float TWO_PI = 6.28318548202514648f;
    float2* E1 = (float2*)e1t;
    float2* E2 = (float2*)e2t;
    if (og == 0) {
        for (int k = 0; k < 12; ++k) {
            float s, c; sincosf(TWO_PI * (xa * (float)k), &s, &c);
            E1[(size_t)k * NPAD + n] = make_float2(c, s);
        }
    } else if (og == 1) {
        for (int k = 12; k < 24; ++k) {
            float s, c; sincosf(TWO_PI * (xa * (float)(k - 24)), &s, &c);
            E1[(size_t)k * NPAD + n] = make_float2(c, s);
        }
    } else if (og == 2) {
        for (int k = 0; k < 12; ++k) {
            float s, c; sincosf(TWO_PI * (xb * (float)k), &s, &c);
            E2[(size_t)k * NPAD + n] = make_float2(c, s);
        }
    } else {
        for (int k = 12; k < 23; ++k) {
            float s, c; sincosf(TWO_PI * (xb * (float)(k - 23)), &s, &c);
            E2[(size_t)k * NPAD + n] = make_float2(c, s);
        }
    }
}

// ---------------------------------------------------------------- project_in v6: LDS-staged phasors, 125 chunks x 160 pts
__global__ void __launch_bounds__(320) k_proj_in(const float* __restrict__ ut,
        const float* __restrict__ e1t, const float* __restrict__ e2t,
        float* __restrict__ partial) {
    __shared__ float2 se1[24][81];   // +1 pad: stride 80 float2 aliases all k to one bank (160%32==0)
    __shared__ float2 se2[23][81];
    int t = threadIdx.x;
    int chunk = blockIdx.x;               // 0..124  (125*160 = 20000 exactly)
    int c0 = blockIdx.y * 8;
    int xm = t / 12, ky = t % 12;
    const float2* E1 = (const float2*)e1t;
    const float2* E2 = (const float2*)e2t;
    float accr[8], acci[8];
    #pragma unroll
    for (int q = 0; q < 8; ++q) { accr[q] = 0.f; acci[q] = 0.f; }
    int n0 = chunk * 160;
    for (int tile = 0; tile < 2; ++tile) {
        int s0 = n0 + tile * 80;
        __syncthreads();
        for (int i = t; i < 1920; i += 320) {
            int k = i / 80, nl = i % 80;
            se1[k][nl] = E1[(size_t)k * NPAD + s0 + nl];
        }
        for (int i = t; i < 1840; i += 320) {
            int k = i / 80, nl = i % 80;
            se2[k][nl] = E2[(size_t)k * NPAD + s0 + nl];
        }
        __syncthreads();
        if (t < 288) {
            for (int nl = 0; nl < 80; ++nl) {
                float2 e1 = se1[xm][nl];
                float2 e2 = se2[ky][nl];
                float br  =  e1.x * e2.x - e1.y * e2.y;
                float nbi = -(e1.x * e2.y + e1.y * e2.x);
                const float4* uv = (const float4*)(ut + (size_t)(s0 + nl) * 64 + c0);
                float4 u0 = uv[0];
                float4 u1 = uv[1];
                accr[0] = fmaf(u0.x, br, accr[0]); acci[0] = fmaf(u0.x, nbi, acci[0]);
                accr[1] = fmaf(u0.y, br, accr[1]); acci[1] = fmaf(u0.y, nbi, acci[1]);
                accr[2] = fmaf(u0.z, br, accr[2]); acci[2] = fmaf(u0.z, nbi, acci[2]);
                accr[3] = fmaf(u0.w, br, accr[3]); acci[3] = fmaf(u0.w, nbi, acci[3]);
                accr[4] = fmaf(u1.x, br, accr[4]); acci[4] = fmaf(u1.x, nbi, acci[4]);
                accr[5] = fmaf(u1.y, br, accr[5]); acci[5] = fmaf(u1.y, nbi, acci[5]);
                accr[6] = fmaf(u1.z, br, accr[6]); acci[6] = fmaf(u1.z, nbi, acci[6]);
                accr[7] = fmaf(u1.w, br, accr[7]); acci[7] = fmaf(u1.w, nbi, acci[7]);
            }
        }
    }
    if (t < 288) {
        float2* pb = (float2*)(partial + (size_t)chunk * 36864);
        #pragma unroll
        for (int q = 0; q < 8; ++q)
            pb[(size_t)(c0 + q) * 288 + t] = make_float2(accr[q], acci[q]);
    }
}

// ---------------------------------------------------------------- project_in stage 2: 125-chunk sum
__global__ void __launch_bounds__(256) k_reduce(const float* __restrict__ partial,
        float* __restrict__ uft) {
    int o = blockIdx.x * 256 + threadIdx.x;   // 0..36863
    float s = 0.f;
    #pragma unroll 5
    for (int ch = 0; ch < 125; ++ch)
        s += partial[(size_t)ch * 36864 + o];
    uft[o] = s;
}

// ---------------------------------------------------------------- channel mix (pin) + 1/9216 fold
__global__ void __launch_bounds__(320) k_mix_in(const float* __restrict__ uft,
        const float* __restrict__ w1re, const float* __restrict__ w1im,
        const float* __restrict__ w2re, const float* __restrict__ w2im,
        float* __restrict__ fmix) {
    int t = threadIdx.x; if (t >= 288) return;
    int o = blockIdx.x;
    int xm = t / 12, ky = t % 12;
    const float *wre, *wim; int xl;
    if (xm < 12) { wre = w1re; wim = w1im; xl = xm; }
    else         { wre = w2re; wim = w2im; xl = xm - 12; }
    float fr = 0.f, fi = 0.f;
    for (int i = 0; i < 64; ++i) {
        float2 u = *(const float2*)(uft + ((size_t)i * 288 + t) * 2);
        int wi_ = ((i * 64 + o) * 12 + xl) * 12 + ky;
        float wr = wre[wi_], wq = wim[wi_];
        fr = fmaf(u.x, wr, fr); fr = fmaf(-u.y, wq, fr);
        fi = fmaf(u.x, wq, fi); fi = fmaf(u.y, wr, fi);
    }
    const float sc = 1.0f / 9216.0f;
    fmix[((size_t)o * 288 + t) * 2]     = fr * sc;
    fmix[((size_t)o * 288 + t) * 2 + 1] = fi * sc;
}

// ---------------------------------------------------------------- sparse irfft2 -> u (single buffer)
__global__ void __launch_bounds__(256) k_igrid(const float* __restrict__ fmix,
        float* __restrict__ u) {
    __shared__ float2 tw[96];
    __shared__ float2 Fs[288];
    __shared__ float2 T[12][24];
    int t = threadIdx.x, c = blockIdx.x;
    int ac0 = blockIdx.y * 24;
    if (t < 96) {
        float s, co; sincosf(6.28318548202514648f * (float)t / 96.0f, &s, &co);
        tw[t] = make_float2(co, s);
    }
    for (int i = t; i < 288; i += 256)
        Fs[i] = *(const float2*)(fmix + ((size_t)c * 288 + i) * 2);
    __syncthreads();
    for (int i = t; i < 288; i += 256) {
        int kyy = i / 24, a = ac0 + (i % 24);
        float tr = 0.f, ti = 0.f;
        int m = 0;
        #pragma unroll
        for (int xx = 0; xx < 12; ++xx) {
            float2 w = tw[m]; float2 f = Fs[xx * 12 + kyy];
            tr += f.x * w.x - f.y * w.y;
            ti += f.x * w.y + f.y * w.x;
            m += a; if (m >= 96) m -= 96;
        }
        m = (84 * a) % 96;
        #pragma unroll
        for (int xx = 12; xx < 24; ++xx) {
            float2 w = tw[m]; float2 f = Fs[xx * 12 + kyy];
            tr += f.x * w.x - f.y * w.y;
            ti += f.x * w.y + f.y * w.x;
            m += a; if (m >= 96) m -= 96;
        }
        T[kyy][i % 24] = make_float2(tr, ti);
    }
    __syncthreads();
    for (int i = t; i < 2304; i += 256) {
        int al = i / 96, j = i % 96;
        float s = T[0][al].x;
        int m = j;
        #pragma unroll
        for (int kyy = 1; kyy < 12; ++kyy) {
            float2 w = tw[m]; float2 tt = T[kyy][al];
            s += 2.0f * (tt.x * w.x - tt.y * w.y);
            m += j; if (m >= 96) m -= 96;
        }
        u[(size_t)c * 9216 + (ac0 + al) * 96 + j] = s;
    }
}

// ---------------------------------------------------------------- FFNO stage A: truncated DFT both dims
__global__ void __launch_bounds__(256) kf_dft(const float* __restrict__ u,
        float* __restrict__ fy, float* __restrict__ fx) {
    __shared__ float us[2400];
    __shared__ float2 tw[96];
    int t = threadIdx.x;
    int c = blockIdx.x, q4 = blockIdx.y, brn = blockIdx.z;
    if (t < 96) {
        float s, co; sincosf(6.28318548202514648f * (float)t / 96.0f, &s, &co);
        tw[t] = make_float2(co, s);
    }
    const float* uc = u + (size_t)c * 9216;
    if (brn == 0) {
        for (int i = t; i < 2304; i += 256) {
            int row = i / 96, col = i % 96;
            us[row * 97 + col] = uc[(q4 * 24 + row) * 96 + col];
        }
    } else {
        for (int i = t; i < 2304; i += 256) {
            int row = i / 24, col = i % 24;
            us[row * 24 + col] = uc[row * 96 + q4 * 24 + col];
        }
    }
    __syncthreads();
    float2* F = (float2*)((brn == 0) ? fy : fx) + (size_t)c * 1152;
    for (int i = t; i < 288; i += 256) {
        int k = i / 24, sl = i % 24;
        int s = q4 * 24 + sl;
        float fr = 0.f, fi = 0.f;
        int m = 0;
        if (brn == 0) {
            for (int r = 0; r < 96; ++r) {
                float uv = us[sl * 97 + r];
                float2 w = tw[m];
                fr = fmaf(uv, w.x, fr); fi = fmaf(-uv, w.y, fi);
                m += k; if (m >= 96) m -= 96;
            }
        } else {
            for (int r = 0; r < 96; ++r) {
                float uv = us[r * 24 + sl];
                float2 w = tw[m];
                fr = fmaf(uv, w.x, fr); fi = fmaf(-uv, w.y, fi);
                m += k; if (m >= 96) m -= 96;
            }
        }
        F[k * 96 + s] = make_float2(fr, fi);
    }
}

// ---------------------------------------------------------------- FFNO stage B: channel mix per mode (split x3)
__global__ void __launch_bounds__(384) kf_mix(const float* __restrict__ fy,
        const float* __restrict__ fx,
        const float* __restrict__ wyre, const float* __restrict__ wyim,
        const float* __restrict__ wxre, const float* __restrict__ wxim,
        float* __restrict__ gy, float* __restrict__ gx) {
    int t = threadIdx.x;
    int o = blockIdx.x, brn = blockIdx.y;
    int idx = blockIdx.z * 384 + t;
    const float2* F = (const float2*)((brn == 0) ? fy : fx);
    const float* wre = (brn == 0) ? wyre : wxre;
    const float* wim = (brn == 0) ? wyim : wxim;
    float2* G = (float2*)((brn == 0) ? gy : gx) + (size_t)o * 1152;
    int k = idx / 96;
    float gr = 0.f, gi = 0.f;
    #pragma unroll 4
    for (int i = 0; i < 64; ++i) {
        float2 f = F[(size_t)i * 1152 + idx];
        int wi_ = (i * 64 + o) * 12 + k;
        float wr = wre[wi_], wq = wim[wi_];
        gr += f.x * wr - f.y * wq;
        gi += f.x * wq + f.y * wr;
    }
    G[idx] = make_float2(gr, gi);
}

// ---------------------------------------------------------------- FFNO stage C: inverse DFTs + residual, in place
__global__ void __launch_bounds__(256) kf_inv(const float* __restrict__ gy,
        const float* __restrict__ gx, float* __restrict__ u) {
    __shared__ float2 sgx[12][96];
    __shared__ float2 sgy[12][24];
    __shared__ float2 tw[96];
    int t = threadIdx.x;
    int c = blockIdx.x, aq = blockIdx.y;
    if (t < 96) {
        float s, co; sincosf(6.28318548202514648f * (float)t / 96.0f, &s, &co);
        tw[t] = make_float2(co, s);
    }
    const float2* Gy = (const float2*)gy + (size_t)c * 1152;
    const float2* Gx = (const float2*)gx + (size_t)c * 1152;
    for (int i = t; i < 1152; i += 256) sgx[i / 96][i % 96] = Gx[i];
    for (int i = t; i < 288; i += 256)
        sgy[i / 24][i % 24] = Gy[(i / 24) * 96 + aq * 24 + (i % 24)];
    __syncthreads();
    const float inv = 1.0f / 96.0f;
    float* uc = u + (size_t)c * 9216;
    for (int idx = t; idx < 2304; idx += 256) {
        int al = idx / 96, j = idx % 96;
        int a = aq * 24 + al;
        float sY = sgy[0][al].x;
        int m = j;
        #pragma unroll
        for (int k = 1; k < 12; ++k) {
            float2 g = sgy[k][al]; float2 w = tw[m];
            sY += 2.0f * (g.x * w.x - g.y * w.y);
            m += j; if (m >= 96) m -= 96;
        }
        float sX = sgx[0][j].x;
        m = a;
        #pragma unroll
        for (int k = 1; k < 12; ++k) {
            float2 g = sgx[k][j]; float2 w = tw[m];
            sX += 2.0f * (g.x * w.x - g.y * w.y);
            m += a; if (m >= 96) m -= 96;
        }
        uc[a * 96 + j] += (sY + sX) * inv;
    }
}

// ---------------------------------------------------------------- forward truncated rfft2 -> uftO
__global__ void __launch_bounds__(512) k_ogrid(const float* __restrict__ u,
        float* __restrict__ uftO) {
    __shared__ float ug[96][97];
    __shared__ float2 P[12][97];
    __shared__ float2 tw[96];
    int t = threadIdx.x, c = blockIdx.x;
    if (t < 96) {
        float s, co; sincosf(6.28318548202514648f * (float)t / 96.0f, &s, &co);
        tw[t] = make_float2(co, s);
    }
    for (int q = 0; q < 18; ++q) {
        int idx = q * 512 + t;
        ug[idx / 96][idx % 96] = u[(size_t)c * 9216 + idx];
    }
    __syncthreads();
    for (int q = 0; q < 3; ++q) {
        int idx = q * 512 + t;
        if (idx < 1152) {
            int ky = idx / 96, a = idx % 96;
            float fr = 0.f, fi = 0.f;
            int m = 0;
            for (int j = 0; j < 96; ++j) {
                float uv = ug[a][j];
                float2 w = tw[m];
                fr = fmaf(uv, w.x, fr); fi = fmaf(-uv, w.y, fi);
                m += ky; if (m >= 96) m -= 96;
            }
            P[ky][a] = make_float2(fr, fi);
        }
    }
    __syncthreads();
    if (t < 288) {
        int x = t / 12, ky = t % 12;
        int k1m = (x < 12) ? x : (x + 72);
        float gr = 0.f, gi = 0.f;
        int m = 0;
        for (int a = 0; a < 96; ++a) {
            float2 p = P[ky][a];
            float2 w = tw[m];
            gr += p.x * w.x + p.y * w.y;
            gi += p.y * w.x - p.x * w.y;
            m += k1m; if (m >= 96) m -= 96;
        }
        uftO[((size_t)c * 288 + t) * 2]     = gr;
        uftO[((size_t)c * 288 + t) * 2 + 1] = gi;
    }
}

// ---------------------------------------------------------------- channel mix (pout) + Hermitian completion
__global__ void __launch_bounds__(320) k_mix_out(const float* __restrict__ uftO,
        const float* __restrict__ w1re, const float* __restrict__ w1im,
        const float* __restrict__ w2re, const float* __restrict__ w2im,
        float* __restrict__ ffull) {
    int t = threadIdx.x; if (t >= 288) return;
    int o = blockIdx.x;
    int xm = t / 12, ky = t % 12;
    const float *wre, *wim; int xl;
    if (xm < 12) { wre = w1re; wim = w1im; xl = xm; }
    else         { wre = w2re; wim = w2im; xl = xm - 12; }
    float fr = 0.f, fi = 0.f;
    for (int i = 0; i < 64; ++i) {
        float2 u = *(const float2*)(uftO + ((size_t)i * 288 + t) * 2);
        int wi_ = ((i * 64 + o) * 12 + xl) * 12 + ky;
        float wr = wre[wi_], wq = wim[wi_];
        fr = fmaf(u.x, wr, fr); fr = fmaf(-u.y, wq, fr);
        fi = fmaf(u.x, wq, fi); fi = fmaf(u.y, wr, fi);
    }
    int M = xm * 23 + ky;
    ffull[((size_t)M * 64 + o) * 2]     = fr;
    ffull[((size_t)M * 64 + o) * 2 + 1] = fi;
    if (ky > 0) {
        int Mc = (23 - xm) * 23 + (23 - ky);
        ffull[((size_t)Mc * 64 + o) * 2]     = fr;
        ffull[((size_t)Mc * 64 + o) * 2 + 1] = -fi;
    }
}

// ---------------------------------------------------------------- project_out v5: e1 reg-cache, c-split x8, mode-split x2
__global__ void __launch_bounds__(256, 4) k_proj_out(const float* __restrict__ ffull,
        const float* __restrict__ e1t, const float* __restrict__ e2t,
        float* __restrict__ uout) {
    int n = blockIdx.x * 256 + threadIdx.x;
    if (n >= G_N) return;
    int c0 = blockIdx.y * 8;
    int x0 = blockIdx.z * 12;
    const float2* E1 = (const float2*)e1t;
    const float2* E2 = (const float2*)e2t;
    float2 e1c[12];
    #pragma unroll
    for (int xi = 0; xi < 12; ++xi)
        e1c[xi] = E1[(size_t)(x0 + xi) * NPAD + n];
    float acc[8];
    #pragma unroll
    for (int q = 0; q < 8; ++q) acc[q] = 0.f;
    for (int y = 0; y < 23; ++y) {
        float2 e2 = E2[(size_t)y * NPAD + n];
        #pragma unroll
        for (int xi = 0; xi < 12; ++xi) {
            float2 e1 = e1c[xi];
            float br  =  e1.x * e2.x - e1.y * e2.y;
            float nbi = -(e1.x * e2.y + e1.y * e2.x);
            const float4* F = (const float4*)(ffull + ((size_t)((x0 + xi) * 23 + y) * 64 + c0) * 2);
            #pragma unroll
            for (int q = 0; q < 4; ++q) {
                float4 f = F[q];
                acc[q*2+0] = fmaf(f.x, br, acc[q*2+0]);
                acc[q*2+0] = fmaf(f.y, nbi, acc[q*2+0]);
                acc[q*2+1] = fmaf(f.z, br, acc[q*2+1]);
                acc[q*2+1] = fmaf(f.w, nbi, acc[q*2+1]);
            }
        }
    }
    float* ub = uout + (size_t)blockIdx.z * 1282048;
    #pragma unroll
    for (int q = 0; q < 8; ++q)
        ub[(size_t)(c0 + q) * NPAD + n] = acc[q];
}

// ---------------------------------------------------------------- head MLP v2: 64 pts/block, 2-phase LDS (anti-spill)
__global__ void __launch_bounds__(256) k_head(const float* __restrict__ uout,
        const float* __restrict__ w1, const float* __restrict__ b1,
        const float* __restrict__ w2, const float* __restrict__ b2,
        float* __restrict__ out) {
    __shared__ float us[64][64];
    __shared__ float s_g[64][64];
    int t = threadIdx.x;
    int p = t & 63;
    int og = __builtin_amdgcn_readfirstlane(t >> 6);
    int nb = blockIdx.x * 64;
    for (int idx = t; idx < 4096; idx += 256) {
        int c = idx >> 6, pp = idx & 63;
        int n = nb + pp;
        int nn = (n < G_N) ? n : 0;
        us[c][pp] = uout[(size_t)c * NPAD + nn] + uout[1282048 + (size_t)c * NPAD + nn];
    }
    __syncthreads();
    #pragma unroll 2
    for (int i = 0; i < 16; ++i) {
        int o = og * 16 + i;
        float h = b1[o];
        for (int c = 0; c < 64; ++c) h = fmaf(us[c][p], w1[c * 64 + o], h);
        s_g[o][p] = gelu_exact(h);
    }
    __syncthreads();
    if (t < 192) {
        int oi = t >> 6;
        float v = b2[oi];
        for (int k = 0; k < 64; ++k) v = fmaf(s_g[k][p], w2[k * 3 + oi], v);
        int n = nb + p;
        if (n < G_N) out[(size_t)oi * G_N + n] = v;
    }
}

// ================================================================ launch
extern "C" void kernel_launch(void* const* d_in, const int* in_sizes, int n_in,
                              void* d_out, int out_size, void* d_ws, size_t ws_size,
                              hipStream_t stream) {
    const float* x        = (const float*)d_in[0];
    const float* coords   = (const float*)d_in[1];
    const float* pre_w1   = (const float*)d_in[2];
    const float* pre_b1   = (const float*)d_in[3];
    const float* pre_w2   = (const float*)d_in[4];
    const float* pre_b2   = (const float*)d_in[5];
    const float* pin_w1_re  = (const float*)d_in[6];
    const float* pin_w1_im  = (const float*)d_in[7];
    const float* pin_w2_re  = (const float*)d_in[8];
    const float* pin_w2_im  = (const float*)d_in[9];
    const float* pout_w1_re = (const float*)d_in[10];
    const float* pout_w1_im = (const float*)d_in[11];
    const float* pout_w2_re = (const float*)d_in[12];
    const float* pout_w2_im = (const float*)d_in[13];
    const float* ifc0w = (const float*)d_in[14];
    const float* ifc0b = (const float*)d_in[15];
    const float* ifncw = (const float*)d_in[16];
    const float* ifncb = (const float*)d_in[17];
    const float* ifc1w = (const float*)d_in[18];
    const float* ifc1b = (const float*)d_in[19];
    const float* ifc2w = (const float*)d_in[20];
    const float* ifc2b = (const float*)d_in[21];
    const float* ifc3w = (const float*)d_in[22];
    const float* ifc3b = (const float*)d_in[23];
    const float* ifc4w = (const float*)d_in[24];
    const float* ifc4b = (const float*)d_in[25];
    const float* wx_re = (const float*)d_in[26];
    const float* wx_im = (const float*)d_in[27];
    const float* wy_re = (const float*)d_in[28];
    const float* wy_im = (const float*)d_in[29];
    const float* hw1 = (const float*)d_in[30];
    const float* hb1 = (const float*)d_in[31];
    const float* hw2 = (const float*)d_in[32];
    const float* hb2 = (const float*)d_in[33];
    float* out = (float*)d_out;
    float* ws  = (float*)d_ws;

    float* ut      = ws + 0;          // [NPAD][64]
    float* ffull   = ws + 0;          // [552][64][2] (alias after ut dead)
    float* e1t     = ws + 1282048;    // [24][NPAD][2]
    float* e2t     = ws + 2243584;    // [23][NPAD][2]
    float* uft     = ws + 3165056;    // [64][288][2]  (later uftO)
    float* fmix    = ws + 3201920;    // [64][288][2]
    float* u       = ws + 3238784;    // [64][96][96]
    float* fy      = ws + 3828608;    // [64][12][96][2]
    float* fx      = ws + 3976064;
    float* gy      = ws + 4123520;
    float* gx      = ws + 4270976;
    float* partial = ws + 3238784;    // [125][36864] floats (alias, dead before u written)
    float* uout    = ws + 3238784;    // 2 x [64][NPAD] (alias after ogrid)

    k_pre<<<dim3(313), dim3(256), 0, stream>>>(x, coords, pre_w1, pre_b1, pre_w2, pre_b2, ut);
    k_iphi<<<dim3(313), dim3(256), 0, stream>>>(coords, ifc0w, ifc0b, ifncw, ifncb,
            ifc1w, ifc1b, ifc2w, ifc2b, ifc3w, ifc3b, ifc4w, ifc4b, e1t, e2t);
    k_proj_in<<<dim3(125, 8), dim3(320), 0, stream>>>(ut, e1t, e2t, partial);
    k_reduce<<<dim3(144), dim3(256), 0, stream>>>(partial, uft);
    k_mix_in<<<dim3(64), dim3(320), 0, stream>>>(uft, pin_w1_re, pin_w1_im, pin_w2_re, pin_w2_im, fmix);
    k_igrid<<<dim3(64, 4), dim3(256), 0, stream>>>(fmix, u);
    for (int L = 0; L < 4; ++L) {
        kf_dft<<<dim3(64, 4, 2), dim3(256), 0, stream>>>(u, fy, fx);
        kf_mix<<<dim3(64, 2, 3), dim3(384), 0, stream>>>(fy, fx,
                wy_re + (size_t)L * 49152, wy_im + (size_t)L * 49152,
                wx_re + (size_t)L * 49152, wx_im + (size_t)L * 49152, gy, gx);
        kf_inv<<<dim3(64, 4), dim3(256), 0, stream>>>(gy, gx, u);
    }
    k_ogrid<<<dim3(64), dim3(512), 0, stream>>>(u, uft /*as uftO*/);
    k_mix_out<<<dim3(64), dim3(320), 0, stream>>>(uft, pout_w1_re, pout_w1_im,
            pout_w2_re, pout_w2_im, ffull);
    k_proj_out<<<dim3(79, 8, 2), dim3(256), 0, stream>>>(ffull, e1t, e2t, uout);
    k_head<<<dim3(313), dim3(256), 0, stream>>>(uout, hw1, hb1, hw2, hb2, out);
}

// Round 11
// 533.697 us; speedup vs baseline: 1.1074x; 1.0200x over previous
//
#include <hip/hip_runtime.h>
#include <math.h>

#define G_N 20000
#define NPAD 20032

static __device__ __forceinline__ float gelu_exact(float t) {
    return 0.5f * t * (1.0f + erff(t * 0.70710678118654752440f));
}

// ---------------------------------------------------------------- pre-MLP v3: 64 pts/block, 2-phase LDS (anti-spill)
__global__ void __launch_bounds__(256) k_pre(const float* __restrict__ x,
        const float* __restrict__ coords,
        const float* __restrict__ w1, const float* __restrict__ b1,
        const float* __restrict__ w2, const float* __restrict__ b2,
        float* __restrict__ ut) {
    __shared__ float s_hid[128][64];
    int t = threadIdx.x;
    int p = t & 63;
    int og = __builtin_amdgcn_readfirstlane(t >> 6);   // wave-uniform
    int nb = blockIdx.x * 64;
    int n = nb + p;
    bool valid = n < G_N;
    int nn = valid ? n : 0;
    float in5[5];
    in5[0] = x[nn]; in5[1] = x[G_N + nn]; in5[2] = x[2 * G_N + nn];
    in5[3] = coords[nn]; in5[4] = coords[G_N + nn];
    #pragma unroll 4
    for (int i = 0; i < 32; ++i) {
        int o = og * 32 + i;
        float h = b1[o];
        #pragma unroll
        for (int d = 0; d < 5; ++d) h = fmaf(in5[d], w1[d * 128 + o], h);
        s_hid[o][p] = gelu_exact(h);
    }
    __syncthreads();
    int c0 = og * 16;
    float acc[16];
    const float4* b4 = (const float4*)(b2 + c0);
    float4 bb;
    bb = b4[0]; acc[0]=bb.x; acc[1]=bb.y; acc[2]=bb.z; acc[3]=bb.w;
    bb = b4[1]; acc[4]=bb.x; acc[5]=bb.y; acc[6]=bb.z; acc[7]=bb.w;
    bb = b4[2]; acc[8]=bb.x; acc[9]=bb.y; acc[10]=bb.z; acc[11]=bb.w;
    bb = b4[3]; acc[12]=bb.x; acc[13]=bb.y; acc[14]=bb.z; acc[15]=bb.w;
    #pragma unroll 2
    for (int o = 0; o < 128; ++o) {
        float a = s_hid[o][p];
        const float4* w4 = (const float4*)(w2 + o * 64 + c0);
        #pragma unroll
        for (int q = 0; q < 4; ++q) {
            float4 w = w4[q];
            acc[q*4+0] = fmaf(a, w.x, acc[q*4+0]);
            acc[q*4+1] = fmaf(a, w.y, acc[q*4+1]);
            acc[q*4+2] = fmaf(a, w.z, acc[q*4+2]);
            acc[q*4+3] = fmaf(a, w.w, acc[q*4+3]);
        }
    }
    if (valid) {
        float4* outp = (float4*)(ut + (size_t)n * 64 + c0);
        #pragma unroll
        for (int q = 0; q < 4; ++q)
            outp[q] = make_float4(acc[q*4+0], acc[q*4+1], acc[q*4+2], acc[q*4+3]);
    }
}

// ---------------------------------------------------------------- IPHI v2: 32 pts/block, tiled LDS GEMM
__shared__ float s_act[128][32];
__shared__ float s_wbuf[32][128];

__device__ __forceinline__ void iphi_gemm(const float* __restrict__ W,
        const float* __restrict__ b, int K, bool dotanh, int t) {
    int po = t & 15, oo = t >> 4;      // 16 pos x 2 pts, 16 groups x 8 outs
    int o0 = oo * 8, p0 = po * 2;
    float acc[8][2];
    #pragma unroll
    for (int q = 0; q < 8; ++q) { acc[q][0] = 0.f; acc[q][1] = 0.f; }
    for (int kc = 0; kc < K; kc += 32) {
        __syncthreads();
        const float4* src = (const float4*)(W + (size_t)kc * 128);
        float4* dst = (float4*)&s_wbuf[0][0];
        #pragma unroll
        for (int i = 0; i < 4; ++i) dst[i * 256 + t] = src[i * 256 + t];
        __syncthreads();
        #pragma unroll 4
        for (int kk = 0; kk < 32; ++kk) {
            float2 a  = *(const float2*)&s_act[kc + kk][p0];
            float4 w0 = *(const float4*)&s_wbuf[kk][o0];
            float4 w1 = *(const float4*)&s_wbuf[kk][o0 + 4];
            float wv[8] = {w0.x, w0.y, w0.z, w0.w, w1.x, w1.y, w1.z, w1.w};
            #pragma unroll
            for (int q = 0; q < 8; ++q) {
                acc[q][0] = fmaf(wv[q], a.x, acc[q][0]);
                acc[q][1] = fmaf(wv[q], a.y, acc[q][1]);
            }
        }
    }
    __syncthreads();
    #pragma unroll
    for (int q = 0; q < 8; ++q) {
        float bo = b[o0 + q];
        float r0 = acc[q][0] + bo, r1 = acc[q][1] + bo;
        if (dotanh) { r0 = tanhf(r0); r1 = tanhf(r1); }
        *(float2*)&s_act[o0 + q][p0] = make_float2(r0, r1);
    }
}

__global__ void __launch_bounds__(256) k_iphi(const float* __restrict__ coords,
        const float* __restrict__ fc0w, const float* __restrict__ fc0b,
        const float* __restrict__ fncw, const float* __restrict__ fncb,
        const float* __restrict__ fc1w, const float* __restrict__ fc1b,
        const float* __restrict__ fc2w, const float* __restrict__ fc2b,
        const float* __restrict__ fc3w, const float* __restrict__ fc3b,
        const float* __restrict__ fc4w, const float* __restrict__ fc4b,
        float* __restrict__ e1t, float* __restrict__ e2t) {
    __shared__ float xdl[4][32];
    __shared__ float ccs[2][32];
    __shared__ float xout[2][32];
    int t = threadIdx.x;
    int nb = blockIdx.x * 32;
    if (t < 32) {
        int n = nb + t; bool v = n < G_N;
        float c0 = v ? coords[n] : 0.5f;
        float c1 = v ? coords[G_N + n] : 0.5f;
        ccs[0][t] = c0; ccs[1][t] = c1;
        float xc0 = c0 - 1e-4f, xc1 = c1 - 1e-4f;
        xdl[0][t] = c0; xdl[1][t] = c1;
        xdl[2][t] = atan2f(xc1, xc0);
        xdl[3][t] = sqrtf(fmaf(xc0, xc0, xc1 * xc1));
    }
    __syncthreads();
    const float PI_F = 3.14159274101257324f;
    #pragma unroll
    for (int i = 0; i < 12; ++i) {          // 96 features x 32 points
        int idx = i * 256 + t;
        int f = idx >> 5, p = idx & 31;
        float v;
        if (f < 32) {
            v = fc0b[f];
            #pragma unroll
            for (int d = 0; d < 4; ++d) v = fmaf(xdl[d][p], fc0w[d * 32 + f], v);
        } else {
            int ff = f - 32;
            int d = (ff >> 3) & 3, j = ff & 7;
            float arg = xdl[d][p] * (PI_F * (float)(1 << j));
            v = (f < 64) ? sinf(arg) : cosf(arg);
        }
        s_act[f][p] = v;
    }
    iphi_gemm(fncw, fncb,  96, false, t);
    iphi_gemm(fc1w, fc1b, 128, true,  t);
    iphi_gemm(fc2w, fc2b, 128, true,  t);
    iphi_gemm(fc3w, fc3b, 128, true,  t);
    __syncthreads();
    if (t < 64) {
        int o = t >> 5, p = t & 31;
        float a = fc4b[o];
        for (int k = 0; k < 128; ++k) a = fmaf(s_act[k][p], fc4w[k * 2 + o], a);
        float c = ccs[o][p];
        xout[o][p] = fmaf(c, a, c);
    }
    __syncthreads();
    const float TWO_PI = 6.28318548202514648f;
    float2* E1 = (float2*)e1t;
    float2* E2 = (float2*)e2t;
    for (int idx = t; idx < 1504; idx += 256) {   // 47 phasors x 32 points
        int k = idx >> 5, p = idx & 31;
        int n = nb + p;
        if (n >= G_N) continue;
        float s, c;
        if (k < 24) {
            int k1 = (k < 12) ? k : (k - 24);
            sincosf(TWO_PI * (xout[0][p] * (float)k1), &s, &c);
            E1[(size_t)k * NPAD + n] = make_float2(c, s);
        } else {
            int kk2 = k - 24;
            int k2 = (kk2 < 12) ? kk2 : (kk2 - 23);
            sincosf(TWO_PI * (xout[1][p] * (float)k2), &s, &c);
            E2[(size_t)kk2 * NPAD + n] = make_float2(c, s);
        }
    }
}

// ---------------------------------------------------------------- project_in v6: LDS-staged phasors, 125 chunks x 160 pts
__global__ void __launch_bounds__(320) k_proj_in(const float* __restrict__ ut,
        const float* __restrict__ e1t, const float* __restrict__ e2t,
        float* __restrict__ partial) {
    __shared__ float2 se1[24][81];   // +1 pad: stride 80 float2 aliases all k to one bank (160%32==0)
    __shared__ float2 se2[23][81];
    int t = threadIdx.x;
    int chunk = blockIdx.x;               // 0..124  (125*160 = 20000 exactly)
    int c0 = blockIdx.y * 8;
    int xm = t / 12, ky = t % 12;
    const float2* E1 = (const float2*)e1t;
    const float2* E2 = (const float2*)e2t;
    float accr[8], acci[8];
    #pragma unroll
    for (int q = 0; q < 8; ++q) { accr[q] = 0.f; acci[q] = 0.f; }
    int n0 = chunk * 160;
    for (int tile = 0; tile < 2; ++tile) {
        int s0 = n0 + tile * 80;
        __syncthreads();
        for (int i = t; i < 1920; i += 320) {
            int k = i / 80, nl = i % 80;
            se1[k][nl] = E1[(size_t)k * NPAD + s0 + nl];
        }
        for (int i = t; i < 1840; i += 320) {
            int k = i / 80, nl = i % 80;
            se2[k][nl] = E2[(size_t)k * NPAD + s0 + nl];
        }
        __syncthreads();
        if (t < 288) {
            for (int nl = 0; nl < 80; ++nl) {
                float2 e1 = se1[xm][nl];
                float2 e2 = se2[ky][nl];
                float br  =  e1.x * e2.x - e1.y * e2.y;
                float nbi = -(e1.x * e2.y + e1.y * e2.x);
                const float4* uv = (const float4*)(ut + (size_t)(s0 + nl) * 64 + c0);
                float4 u0 = uv[0];
                float4 u1 = uv[1];
                accr[0] = fmaf(u0.x, br, accr[0]); acci[0] = fmaf(u0.x, nbi, acci[0]);
                accr[1] = fmaf(u0.y, br, accr[1]); acci[1] = fmaf(u0.y, nbi, acci[1]);
                accr[2] = fmaf(u0.z, br, accr[2]); acci[2] = fmaf(u0.z, nbi, acci[2]);
                accr[3] = fmaf(u0.w, br, accr[3]); acci[3] = fmaf(u0.w, nbi, acci[3]);
                accr[4] = fmaf(u1.x, br, accr[4]); acci[4] = fmaf(u1.x, nbi, acci[4]);
                accr[5] = fmaf(u1.y, br, accr[5]); acci[5] = fmaf(u1.y, nbi, acci[5]);
                accr[6] = fmaf(u1.z, br, accr[6]); acci[6] = fmaf(u1.z, nbi, acci[6]);
                accr[7] = fmaf(u1.w, br, accr[7]); acci[7] = fmaf(u1.w, nbi, acci[7]);
            }
        }
    }
    if (t < 288) {
        float2* pb = (float2*)(partial + (size_t)chunk * 36864);
        #pragma unroll
        for (int q = 0; q < 8; ++q)
            pb[(size_t)(c0 + q) * 288 + t] = make_float2(accr[q], acci[q]);
    }
}

// ---------------------------------------------------------------- project_in stage 2: 125-chunk sum
__global__ void __launch_bounds__(256) k_reduce(const float* __restrict__ partial,
        float* __restrict__ uft) {
    int o = blockIdx.x * 256 + threadIdx.x;   // 0..36863
    float s = 0.f;
    #pragma unroll 5
    for (int ch = 0; ch < 125; ++ch)
        s += partial[(size_t)ch * 36864 + o];
    uft[o] = s;
}

// ---------------------------------------------------------------- channel mix (pin) + 1/9216 fold
__global__ void __launch_bounds__(320) k_mix_in(const float* __restrict__ uft,
        const float* __restrict__ w1re, const float* __restrict__ w1im,
        const float* __restrict__ w2re, const float* __restrict__ w2im,
        float* __restrict__ fmix) {
    int t = threadIdx.x; if (t >= 288) return;
    int o = blockIdx.x;
    int xm = t / 12, ky = t % 12;
    const float *wre, *wim; int xl;
    if (xm < 12) { wre = w1re; wim = w1im; xl = xm; }
    else         { wre = w2re; wim = w2im; xl = xm - 12; }
    float fr = 0.f, fi = 0.f;
    for (int i = 0; i < 64; ++i) {
        float2 u = *(const float2*)(uft + ((size_t)i * 288 + t) * 2);
        int wi_ = ((i * 64 + o) * 12 + xl) * 12 + ky;
        float wr = wre[wi_], wq = wim[wi_];
        fr = fmaf(u.x, wr, fr); fr = fmaf(-u.y, wq, fr);
        fi = fmaf(u.x, wq, fi); fi = fmaf(u.y, wr, fi);
    }
    const float sc = 1.0f / 9216.0f;
    fmix[((size_t)o * 288 + t) * 2]     = fr * sc;
    fmix[((size_t)o * 288 + t) * 2 + 1] = fi * sc;
}

// ---------------------------------------------------------------- sparse irfft2 -> u (single buffer)
__global__ void __launch_bounds__(256) k_igrid(const float* __restrict__ fmix,
        float* __restrict__ u) {
    __shared__ float2 tw[96];
    __shared__ float2 Fs[288];
    __shared__ float2 T[12][24];
    int t = threadIdx.x, c = blockIdx.x;
    int ac0 = blockIdx.y * 24;
    if (t < 96) {
        float s, co; sincosf(6.28318548202514648f * (float)t / 96.0f, &s, &co);
        tw[t] = make_float2(co, s);
    }
    for (int i = t; i < 288; i += 256)
        Fs[i] = *(const float2*)(fmix + ((size_t)c * 288 + i) * 2);
    __syncthreads();
    for (int i = t; i < 288; i += 256) {
        int kyy = i / 24, a = ac0 + (i % 24);
        float tr = 0.f, ti = 0.f;
        int m = 0;
        #pragma unroll
        for (int xx = 0; xx < 12; ++xx) {
            float2 w = tw[m]; float2 f = Fs[xx * 12 + kyy];
            tr += f.x * w.x - f.y * w.y;
            ti += f.x * w.y + f.y * w.x;
            m += a; if (m >= 96) m -= 96;
        }
        m = (84 * a) % 96;
        #pragma unroll
        for (int xx = 12; xx < 24; ++xx) {
            float2 w = tw[m]; float2 f = Fs[xx * 12 + kyy];
            tr += f.x * w.x - f.y * w.y;
            ti += f.x * w.y + f.y * w.x;
            m += a; if (m >= 96) m -= 96;
        }
        T[kyy][i % 24] = make_float2(tr, ti);
    }
    __syncthreads();
    for (int i = t; i < 2304; i += 256) {
        int al = i / 96, j = i % 96;
        float s = T[0][al].x;
        int m = j;
        #pragma unroll
        for (int kyy = 1; kyy < 12; ++kyy) {
            float2 w = tw[m]; float2 tt = T[kyy][al];
            s += 2.0f * (tt.x * w.x - tt.y * w.y);
            m += j; if (m >= 96) m -= 96;
        }
        u[(size_t)c * 9216 + (ac0 + al) * 96 + j] = s;
    }
}

// ---------------------------------------------------------------- FFNO stage A: truncated DFT both dims
__global__ void __launch_bounds__(256) kf_dft(const float* __restrict__ u,
        float* __restrict__ fy, float* __restrict__ fx) {
    __shared__ float us[2400];
    __shared__ float2 tw[96];
    int t = threadIdx.x;
    int c = blockIdx.x, q4 = blockIdx.y, brn = blockIdx.z;
    if (t < 96) {
        float s, co; sincosf(6.28318548202514648f * (float)t / 96.0f, &s, &co);
        tw[t] = make_float2(co, s);
    }
    const float* uc = u + (size_t)c * 9216;
    if (brn == 0) {
        for (int i = t; i < 2304; i += 256) {
            int row = i / 96, col = i % 96;
            us[row * 97 + col] = uc[(q4 * 24 + row) * 96 + col];
        }
    } else {
        for (int i = t; i < 2304; i += 256) {
            int row = i / 24, col = i % 24;
            us[row * 24 + col] = uc[row * 96 + q4 * 24 + col];
        }
    }
    __syncthreads();
    float2* F = (float2*)((brn == 0) ? fy : fx) + (size_t)c * 1152;
    for (int i = t; i < 288; i += 256) {
        int k = i / 24, sl = i % 24;
        int s = q4 * 24 + sl;
        float fr = 0.f, fi = 0.f;
        int m = 0;
        if (brn == 0) {
            for (int r = 0; r < 96; ++r) {
                float uv = us[sl * 97 + r];
                float2 w = tw[m];
                fr = fmaf(uv, w.x, fr); fi = fmaf(-uv, w.y, fi);
                m += k; if (m >= 96) m -= 96;
            }
        } else {
            for (int r = 0; r < 96; ++r) {
                float uv = us[r * 24 + sl];
                float2 w = tw[m];
                fr = fmaf(uv, w.x, fr); fi = fmaf(-uv, w.y, fi);
                m += k; if (m >= 96) m -= 96;
            }
        }
        F[k * 96 + s] = make_float2(fr, fi);
    }
}

// ---------------------------------------------------------------- FFNO stage B: channel mix per mode (split x3)
__global__ void __launch_bounds__(384) kf_mix(const float* __restrict__ fy,
        const float* __restrict__ fx,
        const float* __restrict__ wyre, const float* __restrict__ wyim,
        const float* __restrict__ wxre, const float* __restrict__ wxim,
        float* __restrict__ gy, float* __restrict__ gx) {
    int t = threadIdx.x;
    int o = blockIdx.x, brn = blockIdx.y;
    int idx = blockIdx.z * 384 + t;
    const float2* F = (const float2*)((brn == 0) ? fy : fx);
    const float* wre = (brn == 0) ? wyre : wxre;
    const float* wim = (brn == 0) ? wyim : wxim;
    float2* G = (float2*)((brn == 0) ? gy : gx) + (size_t)o * 1152;
    int k = idx / 96;
    float gr = 0.f, gi = 0.f;
    #pragma unroll 4
    for (int i = 0; i < 64; ++i) {
        float2 f = F[(size_t)i * 1152 + idx];
        int wi_ = (i * 64 + o) * 12 + k;
        float wr = wre[wi_], wq = wim[wi_];
        gr += f.x * wr - f.y * wq;
        gi += f.x * wq + f.y * wr;
    }
    G[idx] = make_float2(gr, gi);
}

// ---------------------------------------------------------------- FFNO stage C: inverse DFTs + residual, in place
__global__ void __launch_bounds__(256) kf_inv(const float* __restrict__ gy,
        const float* __restrict__ gx, float* __restrict__ u) {
    __shared__ float2 sgx[12][96];
    __shared__ float2 sgy[12][24];
    __shared__ float2 tw[96];
    int t = threadIdx.x;
    int c = blockIdx.x, aq = blockIdx.y;
    if (t < 96) {
        float s, co; sincosf(6.28318548202514648f * (float)t / 96.0f, &s, &co);
        tw[t] = make_float2(co, s);
    }
    const float2* Gy = (const float2*)gy + (size_t)c * 1152;
    const float2* Gx = (const float2*)gx + (size_t)c * 1152;
    for (int i = t; i < 1152; i += 256) sgx[i / 96][i % 96] = Gx[i];
    for (int i = t; i < 288; i += 256)
        sgy[i / 24][i % 24] = Gy[(i / 24) * 96 + aq * 24 + (i % 24)];
    __syncthreads();
    const float inv = 1.0f / 96.0f;
    float* uc = u + (size_t)c * 9216;
    for (int idx = t; idx < 2304; idx += 256) {
        int al = idx / 96, j = idx % 96;
        int a = aq * 24 + al;
        float sY = sgy[0][al].x;
        int m = j;
        #pragma unroll
        for (int k = 1; k < 12; ++k) {
            float2 g = sgy[k][al]; float2 w = tw[m];
            sY += 2.0f * (g.x * w.x - g.y * w.y);
            m += j; if (m >= 96) m -= 96;
        }
        float sX = sgx[0][j].x;
        m = a;
        #pragma unroll
        for (int k = 1; k < 12; ++k) {
            float2 g = sgx[k][j]; float2 w = tw[m];
            sX += 2.0f * (g.x * w.x - g.y * w.y);
            m += a; if (m >= 96) m -= 96;
        }
        uc[a * 96 + j] += (sY + sX) * inv;
    }
}

// ---------------------------------------------------------------- forward truncated rfft2 -> uftO
__global__ void __launch_bounds__(512) k_ogrid(const float* __restrict__ u,
        float* __restrict__ uftO) {
    __shared__ float ug[96][97];
    __shared__ float2 P[12][97];
    __shared__ float2 tw[96];
    int t = threadIdx.x, c = blockIdx.x;
    if (t < 96) {
        float s, co; sincosf(6.28318548202514648f * (float)t / 96.0f, &s, &co);
        tw[t] = make_float2(co, s);
    }
    for (int q = 0; q < 18; ++q) {
        int idx = q * 512 + t;
        ug[idx / 96][idx % 96] = u[(size_t)c * 9216 + idx];
    }
    __syncthreads();
    for (int q = 0; q < 3; ++q) {
        int idx = q * 512 + t;
        if (idx < 1152) {
            int ky = idx / 96, a = idx % 96;
            float fr = 0.f, fi = 0.f;
            int m = 0;
            for (int j = 0; j < 96; ++j) {
                float uv = ug[a][j];
                float2 w = tw[m];
                fr = fmaf(uv, w.x, fr); fi = fmaf(-uv, w.y, fi);
                m += ky; if (m >= 96) m -= 96;
            }
            P[ky][a] = make_float2(fr, fi);
        }
    }
    __syncthreads();
    if (t < 288) {
        int x = t / 12, ky = t % 12;
        int k1m = (x < 12) ? x : (x + 72);
        float gr = 0.f, gi = 0.f;
        int m = 0;
        for (int a = 0; a < 96; ++a) {
            float2 p = P[ky][a];
            float2 w = tw[m];
            gr += p.x * w.x + p.y * w.y;
            gi += p.y * w.x - p.x * w.y;
            m += k1m; if (m >= 96) m -= 96;
        }
        uftO[((size_t)c * 288 + t) * 2]     = gr;
        uftO[((size_t)c * 288 + t) * 2 + 1] = gi;
    }
}

// ---------------------------------------------------------------- channel mix (pout) + Hermitian completion
__global__ void __launch_bounds__(320) k_mix_out(const float* __restrict__ uftO,
        const float* __restrict__ w1re, const float* __restrict__ w1im,
        const float* __restrict__ w2re, const float* __restrict__ w2im,
        float* __restrict__ ffull) {
    int t = threadIdx.x; if (t >= 288) return;
    int o = blockIdx.x;
    int xm = t / 12, ky = t % 12;
    const float *wre, *wim; int xl;
    if (xm < 12) { wre = w1re; wim = w1im; xl = xm; }
    else         { wre = w2re; wim = w2im; xl = xm - 12; }
    float fr = 0.f, fi = 0.f;
    for (int i = 0; i < 64; ++i) {
        float2 u = *(const float2*)(uftO + ((size_t)i * 288 + t) * 2);
        int wi_ = ((i * 64 + o) * 12 + xl) * 12 + ky;
        float wr = wre[wi_], wq = wim[wi_];
        fr = fmaf(u.x, wr, fr); fr = fmaf(-u.y, wq, fr);
        fi = fmaf(u.x, wq, fi); fi = fmaf(u.y, wr, fi);
    }
    int M = xm * 23 + ky;
    ffull[((size_t)M * 64 + o) * 2]     = fr;
    ffull[((size_t)M * 64 + o) * 2 + 1] = fi;
    if (ky > 0) {
        int Mc = (23 - xm) * 23 + (23 - ky);
        ffull[((size_t)Mc * 64 + o) * 2]     = fr;
        ffull[((size_t)Mc * 64 + o) * 2 + 1] = -fi;
    }
}

// ---------------------------------------------------------------- project_out v5: e1 reg-cache, c-split x8, mode-split x2
__global__ void __launch_bounds__(256, 4) k_proj_out(const float* __restrict__ ffull,
        const float* __restrict__ e1t, const float* __restrict__ e2t,
        float* __restrict__ uout) {
    int n = blockIdx.x * 256 + threadIdx.x;
    if (n >= G_N) return;
    int c0 = blockIdx.y * 8;
    int x0 = blockIdx.z * 12;
    const float2* E1 = (const float2*)e1t;
    const float2* E2 = (const float2*)e2t;
    float2 e1c[12];
    #pragma unroll
    for (int xi = 0; xi < 12; ++xi)
        e1c[xi] = E1[(size_t)(x0 + xi) * NPAD + n];
    float acc[8];
    #pragma unroll
    for (int q = 0; q < 8; ++q) acc[q] = 0.f;
    for (int y = 0; y < 23; ++y) {
        float2 e2 = E2[(size_t)y * NPAD + n];
        #pragma unroll
        for (int xi = 0; xi < 12; ++xi) {
            float2 e1 = e1c[xi];
            float br  =  e1.x * e2.x - e1.y * e2.y;
            float nbi = -(e1.x * e2.y + e1.y * e2.x);
            const float4* F = (const float4*)(ffull + ((size_t)((x0 + xi) * 23 + y) * 64 + c0) * 2);
            #pragma unroll
            for (int q = 0; q < 4; ++q) {
                float4 f = F[q];
                acc[q*2+0] = fmaf(f.x, br, acc[q*2+0]);
                acc[q*2+0] = fmaf(f.y, nbi, acc[q*2+0]);
                acc[q*2+1] = fmaf(f.z, br, acc[q*2+1]);
                acc[q*2+1] = fmaf(f.w, nbi, acc[q*2+1]);
            }
        }
    }
    float* ub = uout + (size_t)blockIdx.z * 1282048;
    #pragma unroll
    for (int q = 0; q < 8; ++q)
        ub[(size_t)(c0 + q) * NPAD + n] = acc[q];
}

// ---------------------------------------------------------------- head MLP v2: 64 pts/block, 2-phase LDS (anti-spill)
__global__ void __launch_bounds__(256) k_head(const float* __restrict__ uout,
        const float* __restrict__ w1, const float* __restrict__ b1,
        const float* __restrict__ w2, const float* __restrict__ b2,
        float* __restrict__ out) {
    __shared__ float us[64][64];
    __shared__ float s_g[64][64];
    int t = threadIdx.x;
    int p = t & 63;
    int og = __builtin_amdgcn_readfirstlane(t >> 6);
    int nb = blockIdx.x * 64;
    for (int idx = t; idx < 4096; idx += 256) {
        int c = idx >> 6, pp = idx & 63;
        int n = nb + pp;
        int nn = (n < G_N) ? n : 0;
        us[c][pp] = uout[(size_t)c * NPAD + nn] + uout[1282048 + (size_t)c * NPAD + nn];
    }
    __syncthreads();
    #pragma unroll 2
    for (int i = 0; i < 16; ++i) {
        int o = og * 16 + i;
        float h = b1[o];
        for (int c = 0; c < 64; ++c) h = fmaf(us[c][p], w1[c * 64 + o], h);
        s_g[o][p] = gelu_exact(h);
    }
    __syncthreads();
    if (t < 192) {
        int oi = t >> 6;
        float v = b2[oi];
        for (int k = 0; k < 64; ++k) v = fmaf(s_g[k][p], w2[k * 3 + oi], v);
        int n = nb + p;
        if (n < G_N) out[(size_t)oi * G_N + n] = v;
    }
}

// ================================================================ launch
extern "C" void kernel_launch(void* const* d_in, const int* in_sizes, int n_in,
                              void* d_out, int out_size, void* d_ws, size_t ws_size,
                              hipStream_t stream) {
    const float* x        = (const float*)d_in[0];
    const float* coords   = (const float*)d_in[1];
    const float* pre_w1   = (const float*)d_in[2];
    const float* pre_b1   = (const float*)d_in[3];
    const float* pre_w2   = (const float*)d_in[4];
    const float* pre_b2   = (const float*)d_in[5];
    const float* pin_w1_re  = (const float*)d_in[6];
    const float* pin_w1_im  = (const float*)d_in[7];
    const float* pin_w2_re  = (const float*)d_in[8];
    const float* pin_w2_im  = (const float*)d_in[9];
    const float* pout_w1_re = (const float*)d_in[10];
    const float* pout_w1_im = (const float*)d_in[11];
    const float* pout_w2_re = (const float*)d_in[12];
    const float* pout_w2_im = (const float*)d_in[13];
    const float* ifc0w = (const float*)d_in[14];
    const float* ifc0b = (const float*)d_in[15];
    const float* ifncw = (const float*)d_in[16];
    const float* ifncb = (const float*)d_in[17];
    const float* ifc1w = (const float*)d_in[18];
    const float* ifc1b = (const float*)d_in[19];
    const float* ifc2w = (const float*)d_in[20];
    const float* ifc2b = (const float*)d_in[21];
    const float* ifc3w = (const float*)d_in[22];
    const float* ifc3b = (const float*)d_in[23];
    const float* ifc4w = (const float*)d_in[24];
    const float* ifc4b = (const float*)d_in[25];
    const float* wx_re = (const float*)d_in[26];
    const float* wx_im = (const float*)d_in[27];
    const float* wy_re = (const float*)d_in[28];
    const float* wy_im = (const float*)d_in[29];
    const float* hw1 = (const float*)d_in[30];
    const float* hb1 = (const float*)d_in[31];
    const float* hw2 = (const float*)d_in[32];
    const float* hb2 = (const float*)d_in[33];
    float* out = (float*)d_out;
    float* ws  = (float*)d_ws;

    float* ut      = ws + 0;          // [NPAD][64]
    float* ffull   = ws + 0;          // [552][64][2] (alias after ut dead)
    float* e1t     = ws + 1282048;    // [24][NPAD][2]
    float* e2t     = ws + 2243584;    // [23][NPAD][2]
    float* uft     = ws + 3165056;    // [64][288][2]  (later uftO)
    float* fmix    = ws + 3201920;    // [64][288][2]
    float* u       = ws + 3238784;    // [64][96][96]
    float* fy      = ws + 3828608;    // [64][12][96][2]
    float* fx      = ws + 3976064;
    float* gy      = ws + 4123520;
    float* gx      = ws + 4270976;
    float* partial = ws + 3238784;    // [125][36864] floats (alias, dead before u written)
    float* uout    = ws + 3238784;    // 2 x [64][NPAD] (alias after ogrid)

    k_pre<<<dim3(313), dim3(256), 0, stream>>>(x, coords, pre_w1, pre_b1, pre_w2, pre_b2, ut);
    k_iphi<<<dim3(625), dim3(256), 0, stream>>>(coords, ifc0w, ifc0b, ifncw, ifncb,
            ifc1w, ifc1b, ifc2w, ifc2b, ifc3w, ifc3b, ifc4w, ifc4b, e1t, e2t);
    k_proj_in<<<dim3(125, 8), dim3(320), 0, stream>>>(ut, e1t, e2t, partial);
    k_reduce<<<dim3(144), dim3(256), 0, stream>>>(partial, uft);
    k_mix_in<<<dim3(64), dim3(320), 0, stream>>>(uft, pin_w1_re, pin_w1_im, pin_w2_re, pin_w2_im, fmix);
    k_igrid<<<dim3(64, 4), dim3(256), 0, stream>>>(fmix, u);
    for (int L = 0; L < 4; ++L) {
        kf_dft<<<dim3(64, 4, 2), dim3(256), 0, stream>>>(u, fy, fx);
        kf_mix<<<dim3(64, 2, 3), dim3(384), 0, stream>>>(fy, fx,
                wy_re + (size_t)L * 49152, wy_im + (size_t)L * 49152,
                wx_re + (size_t)L * 49152, wx_im + (size_t)L * 49152, gy, gx);
        kf_inv<<<dim3(64, 4), dim3(256), 0, stream>>>(gy, gx, u);
    }
    k_ogrid<<<dim3(64), dim3(512), 0, stream>>>(u, uft /*as uftO*/);
    k_mix_out<<<dim3(64), dim3(320), 0, stream>>>(uft, pout_w1_re, pout_w1_im,
            pout_w2_re, pout_w2_im, ffull);
    k_proj_out<<<dim3(79, 8, 2), dim3(256), 0, stream>>>(ffull, e1t, e2t, uout);
    k_head<<<dim3(313), dim3(256), 0, stream>>>(uout, hw1, hb1, hw2, hb2, out);
}

// Round 12
// 524.334 us; speedup vs baseline: 1.1272x; 1.0179x over previous
//
#include <hip/hip_runtime.h>
#include <math.h>

#define G_N 20000
#define NPAD 20032

static __device__ __forceinline__ float gelu_exact(float t) {
    return 0.5f * t * (1.0f + erff(t * 0.70710678118654752440f));
}

// ---------------------------------------------------------------- pre-MLP v3: 64 pts/block, 2-phase LDS (anti-spill)
__global__ void __launch_bounds__(256) k_pre(const float* __restrict__ x,
        const float* __restrict__ coords,
        const float* __restrict__ w1, const float* __restrict__ b1,
        const float* __restrict__ w2, const float* __restrict__ b2,
        float* __restrict__ ut) {
    __shared__ float s_hid[128][64];
    int t = threadIdx.x;
    int p = t & 63;
    int og = __builtin_amdgcn_readfirstlane(t >> 6);   // wave-uniform
    int nb = blockIdx.x * 64;
    int n = nb + p;
    bool valid = n < G_N;
    int nn = valid ? n : 0;
    float in5[5];
    in5[0] = x[nn]; in5[1] = x[G_N + nn]; in5[2] = x[2 * G_N + nn];
    in5[3] = coords[nn]; in5[4] = coords[G_N + nn];
    #pragma unroll 4
    for (int i = 0; i < 32; ++i) {
        int o = og * 32 + i;
        float h = b1[o];
        #pragma unroll
        for (int d = 0; d < 5; ++d) h = fmaf(in5[d], w1[d * 128 + o], h);
        s_hid[o][p] = gelu_exact(h);
    }
    __syncthreads();
    int c0 = og * 16;
    float acc[16];
    const float4* b4 = (const float4*)(b2 + c0);
    float4 bb;
    bb = b4[0]; acc[0]=bb.x; acc[1]=bb.y; acc[2]=bb.z; acc[3]=bb.w;
    bb = b4[1]; acc[4]=bb.x; acc[5]=bb.y; acc[6]=bb.z; acc[7]=bb.w;
    bb = b4[2]; acc[8]=bb.x; acc[9]=bb.y; acc[10]=bb.z; acc[11]=bb.w;
    bb = b4[3]; acc[12]=bb.x; acc[13]=bb.y; acc[14]=bb.z; acc[15]=bb.w;
    #pragma unroll 2
    for (int o = 0; o < 128; ++o) {
        float a = s_hid[o][p];
        const float4* w4 = (const float4*)(w2 + o * 64 + c0);
        #pragma unroll
        for (int q = 0; q < 4; ++q) {
            float4 w = w4[q];
            acc[q*4+0] = fmaf(a, w.x, acc[q*4+0]);
            acc[q*4+1] = fmaf(a, w.y, acc[q*4+1]);
            acc[q*4+2] = fmaf(a, w.z, acc[q*4+2]);
            acc[q*4+3] = fmaf(a, w.w, acc[q*4+3]);
        }
    }
    if (valid) {
        float4* outp = (float4*)(ut + (size_t)n * 64 + c0);
        #pragma unroll
        for (int q = 0; q < 4; ++q)
            outp[q] = make_float4(acc[q*4+0], acc[q*4+1], acc[q*4+2], acc[q*4+3]);
    }
}

// ---------------------------------------------------------------- IPHI v2: 32 pts/block, tiled LDS GEMM
__shared__ float s_act[128][32];
__shared__ float s_wbuf[32][128];

__device__ __forceinline__ void iphi_gemm(const float* __restrict__ W,
        const float* __restrict__ b, int K, bool dotanh, int t) {
    int po = t & 15, oo = t >> 4;      // 16 pos x 2 pts, 16 groups x 8 outs
    int o0 = oo * 8, p0 = po * 2;
    float acc[8][2];
    #pragma unroll
    for (int q = 0; q < 8; ++q) { acc[q][0] = 0.f; acc[q][1] = 0.f; }
    for (int kc = 0; kc < K; kc += 32) {
        __syncthreads();
        const float4* src = (const float4*)(W + (size_t)kc * 128);
        float4* dst = (float4*)&s_wbuf[0][0];
        #pragma unroll
        for (int i = 0; i < 4; ++i) dst[i * 256 + t] = src[i * 256 + t];
        __syncthreads();
        #pragma unroll 4
        for (int kk = 0; kk < 32; ++kk) {
            float2 a  = *(const float2*)&s_act[kc + kk][p0];
            float4 w0 = *(const float4*)&s_wbuf[kk][o0];
            float4 w1 = *(const float4*)&s_wbuf[kk][o0 + 4];
            float wv[8] = {w0.x, w0.y, w0.z, w0.w, w1.x, w1.y, w1.z, w1.w};
            #pragma unroll
            for (int q = 0; q < 8; ++q) {
                acc[q][0] = fmaf(wv[q], a.x, acc[q][0]);
                acc[q][1] = fmaf(wv[q], a.y, acc[q][1]);
            }
        }
    }
    __syncthreads();
    #pragma unroll
    for (int q = 0; q < 8; ++q) {
        float bo = b[o0 + q];
        float r0 = acc[q][0] + bo, r1 = acc[q][1] + bo;
        if (dotanh) { r0 = tanhf(r0); r1 = tanhf(r1); }
        *(float2*)&s_act[o0 + q][p0] = make_float2(r0, r1);
    }
}

__global__ void __launch_bounds__(256) k_iphi(const float* __restrict__ coords,
        const float* __restrict__ fc0w, const float* __restrict__ fc0b,
        const float* __restrict__ fncw, const float* __restrict__ fncb,
        const float* __restrict__ fc1w, const float* __restrict__ fc1b,
        const float* __restrict__ fc2w, const float* __restrict__ fc2b,
        const float* __restrict__ fc3w, const float* __restrict__ fc3b,
        const float* __restrict__ fc4w, const float* __restrict__ fc4b,
        float* __restrict__ e1t, float* __restrict__ e2t) {
    __shared__ float xdl[4][32];
    __shared__ float ccs[2][32];
    __shared__ float xout[2][32];
    int t = threadIdx.x;
    int nb = blockIdx.x * 32;
    if (t < 32) {
        int n = nb + t; bool v = n < G_N;
        float c0 = v ? coords[n] : 0.5f;
        float c1 = v ? coords[G_N + n] : 0.5f;
        ccs[0][t] = c0; ccs[1][t] = c1;
        float xc0 = c0 - 1e-4f, xc1 = c1 - 1e-4f;
        xdl[0][t] = c0; xdl[1][t] = c1;
        xdl[2][t] = atan2f(xc1, xc0);
        xdl[3][t] = sqrtf(fmaf(xc0, xc0, xc1 * xc1));
    }
    __syncthreads();
    const float PI_F = 3.14159274101257324f;
    #pragma unroll
    for (int i = 0; i < 12; ++i) {          // 96 features x 32 points
        int idx = i * 256 + t;
        int f = idx >> 5, p = idx & 31;
        float v;
        if (f < 32) {
            v = fc0b[f];
            #pragma unroll
            for (int d = 0; d < 4; ++d) v = fmaf(xdl[d][p], fc0w[d * 32 + f], v);
        } else {
            int ff = f - 32;
            int d = (ff >> 3) & 3, j = ff & 7;
            float arg = xdl[d][p] * (PI_F * (float)(1 << j));
            v = (f < 64) ? sinf(arg) : cosf(arg);
        }
        s_act[f][p] = v;
    }
    iphi_gemm(fncw, fncb,  96, false, t);
    iphi_gemm(fc1w, fc1b, 128, true,  t);
    iphi_gemm(fc2w, fc2b, 128, true,  t);
    iphi_gemm(fc3w, fc3b, 128, true,  t);
    __syncthreads();
    if (t < 64) {
        int o = t >> 5, p = t & 31;
        float a = fc4b[o];
        for (int k = 0; k < 128; ++k) a = fmaf(s_act[k][p], fc4w[k * 2 + o], a);
        float c = ccs[o][p];
        xout[o][p] = fmaf(c, a, c);
    }
    __syncthreads();
    const float TWO_PI = 6.28318548202514648f;
    float2* E1 = (float2*)e1t;
    float2* E2 = (float2*)e2t;
    for (int idx = t; idx < 1504; idx += 256) {   // 47 phasors x 32 points
        int k = idx >> 5, p = idx & 31;
        int n = nb + p;
        if (n >= G_N) continue;
        float s, c;
        if (k < 24) {
            int k1 = (k < 12) ? k : (k - 24);
            sincosf(TWO_PI * (xout[0][p] * (float)k1), &s, &c);
            E1[(size_t)k * NPAD + n] = make_float2(c, s);
        } else {
            int kk2 = k - 24;
            int k2 = (kk2 < 12) ? kk2 : (kk2 - 23);
            sincosf(TWO_PI * (xout[1][p] * (float)k2), &s, &c);
            E2[(size_t)kk2 * NPAD + n] = make_float2(c, s);
        }
    }
}

// ---------------------------------------------------------------- project_in v6: LDS-staged phasors, 125 chunks x 160 pts
__global__ void __launch_bounds__(320) k_proj_in(const float* __restrict__ ut,
        const float* __restrict__ e1t, const float* __restrict__ e2t,
        float* __restrict__ partial) {
    __shared__ float2 se1[24][81];   // +1 pad: stride 80 float2 aliases all k to one bank (160%32==0)
    __shared__ float2 se2[23][81];
    int t = threadIdx.x;
    int chunk = blockIdx.x;               // 0..124  (125*160 = 20000 exactly)
    int c0 = blockIdx.y * 8;
    int xm = t / 12, ky = t % 12;
    const float2* E1 = (const float2*)e1t;
    const float2* E2 = (const float2*)e2t;
    float accr[8], acci[8];
    #pragma unroll
    for (int q = 0; q < 8; ++q) { accr[q] = 0.f; acci[q] = 0.f; }
    int n0 = chunk * 160;
    for (int tile = 0; tile < 2; ++tile) {
        int s0 = n0 + tile * 80;
        __syncthreads();
        for (int i = t; i < 1920; i += 320) {
            int k = i / 80, nl = i % 80;
            se1[k][nl] = E1[(size_t)k * NPAD + s0 + nl];
        }
        for (int i = t; i < 1840; i += 320) {
            int k = i / 80, nl = i % 80;
            se2[k][nl] = E2[(size_t)k * NPAD + s0 + nl];
        }
        __syncthreads();
        if (t < 288) {
            for (int nl = 0; nl < 80; ++nl) {
                float2 e1 = se1[xm][nl];
                float2 e2 = se2[ky][nl];
                float br  =  e1.x * e2.x - e1.y * e2.y;
                float nbi = -(e1.x * e2.y + e1.y * e2.x);
                const float4* uv = (const float4*)(ut + (size_t)(s0 + nl) * 64 + c0);
                float4 u0 = uv[0];
                float4 u1 = uv[1];
                accr[0] = fmaf(u0.x, br, accr[0]); acci[0] = fmaf(u0.x, nbi, acci[0]);
                accr[1] = fmaf(u0.y, br, accr[1]); acci[1] = fmaf(u0.y, nbi, acci[1]);
                accr[2] = fmaf(u0.z, br, accr[2]); acci[2] = fmaf(u0.z, nbi, acci[2]);
                accr[3] = fmaf(u0.w, br, accr[3]); acci[3] = fmaf(u0.w, nbi, acci[3]);
                accr[4] = fmaf(u1.x, br, accr[4]); acci[4] = fmaf(u1.x, nbi, acci[4]);
                accr[5] = fmaf(u1.y, br, accr[5]); acci[5] = fmaf(u1.y, nbi, acci[5]);
                accr[6] = fmaf(u1.z, br, accr[6]); acci[6] = fmaf(u1.z, nbi, acci[6]);
                accr[7] = fmaf(u1.w, br, accr[7]); acci[7] = fmaf(u1.w, nbi, acci[7]);
            }
        }
    }
    if (t < 288) {
        float2* pb = (float2*)(partial + (size_t)chunk * 36864);
        #pragma unroll
        for (int q = 0; q < 8; ++q)
            pb[(size_t)(c0 + q) * 288 + t] = make_float2(accr[q], acci[q]);
    }
}

// ---------------------------------------------------------------- project_in stage 2: 125-chunk sum
__global__ void __launch_bounds__(256) k_reduce(const float* __restrict__ partial,
        float* __restrict__ uft) {
    int o = blockIdx.x * 256 + threadIdx.x;   // 0..36863
    float s = 0.f;
    #pragma unroll 5
    for (int ch = 0; ch < 125; ++ch)
        s += partial[(size_t)ch * 36864 + o];
    uft[o] = s;
}

// ---------------------------------------------------------------- channel mix (pin) + 1/9216 fold
__global__ void __launch_bounds__(320) k_mix_in(const float* __restrict__ uft,
        const float* __restrict__ w1re, const float* __restrict__ w1im,
        const float* __restrict__ w2re, const float* __restrict__ w2im,
        float* __restrict__ fmix) {
    int t = threadIdx.x; if (t >= 288) return;
    int o = blockIdx.x;
    int xm = t / 12, ky = t % 12;
    const float *wre, *wim; int xl;
    if (xm < 12) { wre = w1re; wim = w1im; xl = xm; }
    else         { wre = w2re; wim = w2im; xl = xm - 12; }
    float fr = 0.f, fi = 0.f;
    for (int i = 0; i < 64; ++i) {
        float2 u = *(const float2*)(uft + ((size_t)i * 288 + t) * 2);
        int wi_ = ((i * 64 + o) * 12 + xl) * 12 + ky;
        float wr = wre[wi_], wq = wim[wi_];
        fr = fmaf(u.x, wr, fr); fr = fmaf(-u.y, wq, fr);
        fi = fmaf(u.x, wq, fi); fi = fmaf(u.y, wr, fi);
    }
    const float sc = 1.0f / 9216.0f;
    fmix[((size_t)o * 288 + t) * 2]     = fr * sc;
    fmix[((size_t)o * 288 + t) * 2 + 1] = fi * sc;
}

// ---------------------------------------------------------------- sparse irfft2 -> u (single buffer)
__global__ void __launch_bounds__(256) k_igrid(const float* __restrict__ fmix,
        float* __restrict__ u) {
    __shared__ float2 tw[96];
    __shared__ float2 Fs[288];
    __shared__ float2 T[12][24];
    int t = threadIdx.x, c = blockIdx.x;
    int ac0 = blockIdx.y * 24;
    if (t < 96) {
        float s, co; sincosf(6.28318548202514648f * (float)t / 96.0f, &s, &co);
        tw[t] = make_float2(co, s);
    }
    for (int i = t; i < 288; i += 256)
        Fs[i] = *(const float2*)(fmix + ((size_t)c * 288 + i) * 2);
    __syncthreads();
    for (int i = t; i < 288; i += 256) {
        int kyy = i / 24, a = ac0 + (i % 24);
        float tr = 0.f, ti = 0.f;
        int m = 0;
        #pragma unroll
        for (int xx = 0; xx < 12; ++xx) {
            float2 w = tw[m]; float2 f = Fs[xx * 12 + kyy];
            tr += f.x * w.x - f.y * w.y;
            ti += f.x * w.y + f.y * w.x;
            m += a; if (m >= 96) m -= 96;
        }
        m = (84 * a) % 96;
        #pragma unroll
        for (int xx = 12; xx < 24; ++xx) {
            float2 w = tw[m]; float2 f = Fs[xx * 12 + kyy];
            tr += f.x * w.x - f.y * w.y;
            ti += f.x * w.y + f.y * w.x;
            m += a; if (m >= 96) m -= 96;
        }
        T[kyy][i % 24] = make_float2(tr, ti);
    }
    __syncthreads();
    for (int i = t; i < 2304; i += 256) {
        int al = i / 96, j = i % 96;
        float s = T[0][al].x;
        int m = j;
        #pragma unroll
        for (int kyy = 1; kyy < 12; ++kyy) {
            float2 w = tw[m]; float2 tt = T[kyy][al];
            s += 2.0f * (tt.x * w.x - tt.y * w.y);
            m += j; if (m >= 96) m -= 96;
        }
        u[(size_t)c * 9216 + (ac0 + al) * 96 + j] = s;
    }
}

// ---------------------------------------------------------------- FFNO stage A: truncated DFT both dims
__global__ void __launch_bounds__(256) kf_dft(const float* __restrict__ u,
        float* __restrict__ fy, float* __restrict__ fx) {
    __shared__ float us[2400];
    __shared__ float2 tw[96];
    int t = threadIdx.x;
    int c = blockIdx.x, q4 = blockIdx.y, brn = blockIdx.z;
    if (t < 96) {
        float s, co; sincosf(6.28318548202514648f * (float)t / 96.0f, &s, &co);
        tw[t] = make_float2(co, s);
    }
    const float* uc = u + (size_t)c * 9216;
    if (brn == 0) {
        for (int i = t; i < 2304; i += 256) {
            int row = i / 96, col = i % 96;
            us[row * 97 + col] = uc[(q4 * 24 + row) * 96 + col];
        }
    } else {
        for (int i = t; i < 2304; i += 256) {
            int row = i / 24, col = i % 24;
            us[row * 24 + col] = uc[row * 96 + q4 * 24 + col];
        }
    }
    __syncthreads();
    float2* F = (float2*)((brn == 0) ? fy : fx) + (size_t)c * 1152;
    for (int i = t; i < 288; i += 256) {
        int k = i / 24, sl = i % 24;
        int s = q4 * 24 + sl;
        float fr = 0.f, fi = 0.f;
        int m = 0;
        if (brn == 0) {
            for (int r = 0; r < 96; ++r) {
                float uv = us[sl * 97 + r];
                float2 w = tw[m];
                fr = fmaf(uv, w.x, fr); fi = fmaf(-uv, w.y, fi);
                m += k; if (m >= 96) m -= 96;
            }
        } else {
            for (int r = 0; r < 96; ++r) {
                float uv = us[r * 24 + sl];
                float2 w = tw[m];
                fr = fmaf(uv, w.x, fr); fi = fmaf(-uv, w.y, fi);
                m += k; if (m >= 96) m -= 96;
            }
        }
        F[k * 96 + s] = make_float2(fr, fi);
    }
}

// ---------------------------------------------------------------- FFNO stage B: channel mix per mode (split x3)
__global__ void __launch_bounds__(384) kf_mix(const float* __restrict__ fy,
        const float* __restrict__ fx,
        const float* __restrict__ wyre, const float* __restrict__ wyim,
        const float* __restrict__ wxre, const float* __restrict__ wxim,
        float* __restrict__ gy, float* __restrict__ gx) {
    int t = threadIdx.x;
    int o = blockIdx.x, brn = blockIdx.y;
    int idx = blockIdx.z * 384 + t;
    const float2* F = (const float2*)((brn == 0) ? fy : fx);
    const float* wre = (brn == 0) ? wyre : wxre;
    const float* wim = (brn == 0) ? wyim : wxim;
    float2* G = (float2*)((brn == 0) ? gy : gx) + (size_t)o * 1152;
    int k = idx / 96;
    float gr = 0.f, gi = 0.f;
    #pragma unroll 4
    for (int i = 0; i < 64; ++i) {
        float2 f = F[(size_t)i * 1152 + idx];
        int wi_ = (i * 64 + o) * 12 + k;
        float wr = wre[wi_], wq = wim[wi_];
        gr += f.x * wr - f.y * wq;
        gi += f.x * wq + f.y * wr;
    }
    G[idx] = make_float2(gr, gi);
}

// ---------------------------------------------------------------- FFNO stage C: inverse DFTs + residual, in place
__global__ void __launch_bounds__(256) kf_inv(const float* __restrict__ gy,
        const float* __restrict__ gx, float* __restrict__ u) {
    __shared__ float2 sgx[12][96];
    __shared__ float2 sgy[12][24];
    __shared__ float2 tw[96];
    int t = threadIdx.x;
    int c = blockIdx.x, aq = blockIdx.y;
    if (t < 96) {
        float s, co; sincosf(6.28318548202514648f * (float)t / 96.0f, &s, &co);
        tw[t] = make_float2(co, s);
    }
    const float2* Gy = (const float2*)gy + (size_t)c * 1152;
    const float2* Gx = (const float2*)gx + (size_t)c * 1152;
    for (int i = t; i < 1152; i += 256) sgx[i / 96][i % 96] = Gx[i];
    for (int i = t; i < 288; i += 256)
        sgy[i / 24][i % 24] = Gy[(i / 24) * 96 + aq * 24 + (i % 24)];
    __syncthreads();
    const float inv = 1.0f / 96.0f;
    float* uc = u + (size_t)c * 9216;
    for (int idx = t; idx < 2304; idx += 256) {
        int al = idx / 96, j = idx % 96;
        int a = aq * 24 + al;
        float sY = sgy[0][al].x;
        int m = j;
        #pragma unroll
        for (int k = 1; k < 12; ++k) {
            float2 g = sgy[k][al]; float2 w = tw[m];
            sY += 2.0f * (g.x * w.x - g.y * w.y);
            m += j; if (m >= 96) m -= 96;
        }
        float sX = sgx[0][j].x;
        m = a;
        #pragma unroll
        for (int k = 1; k < 12; ++k) {
            float2 g = sgx[k][j]; float2 w = tw[m];
            sX += 2.0f * (g.x * w.x - g.y * w.y);
            m += a; if (m >= 96) m -= 96;
        }
        uc[a * 96 + j] += (sY + sX) * inv;
    }
}

// ---------------------------------------------------------------- forward truncated rfft2 -> uftO
__global__ void __launch_bounds__(512) k_ogrid(const float* __restrict__ u,
        float* __restrict__ uftO) {
    __shared__ float ug[96][97];
    __shared__ float2 P[12][97];
    __shared__ float2 tw[96];
    int t = threadIdx.x, c = blockIdx.x;
    if (t < 96) {
        float s, co; sincosf(6.28318548202514648f * (float)t / 96.0f, &s, &co);
        tw[t] = make_float2(co, s);
    }
    for (int q = 0; q < 18; ++q) {
        int idx = q * 512 + t;
        ug[idx / 96][idx % 96] = u[(size_t)c * 9216 + idx];
    }
    __syncthreads();
    for (int q = 0; q < 3; ++q) {
        int idx = q * 512 + t;
        if (idx < 1152) {
            int ky = idx / 96, a = idx % 96;
            float fr = 0.f, fi = 0.f;
            int m = 0;
            for (int j = 0; j < 96; ++j) {
                float uv = ug[a][j];
                float2 w = tw[m];
                fr = fmaf(uv, w.x, fr); fi = fmaf(-uv, w.y, fi);
                m += ky; if (m >= 96) m -= 96;
            }
            P[ky][a] = make_float2(fr, fi);
        }
    }
    __syncthreads();
    if (t < 288) {
        int x = t / 12, ky = t % 12;
        int k1m = (x < 12) ? x : (x + 72);
        float gr = 0.f, gi = 0.f;
        int m = 0;
        for (int a = 0; a < 96; ++a) {
            float2 p = P[ky][a];
            float2 w = tw[m];
            gr += p.x * w.x + p.y * w.y;
            gi += p.y * w.x - p.x * w.y;
            m += k1m; if (m >= 96) m -= 96;
        }
        uftO[((size_t)c * 288 + t) * 2]     = gr;
        uftO[((size_t)c * 288 + t) * 2 + 1] = gi;
    }
}

// ---------------------------------------------------------------- channel mix (pout) + Hermitian completion
__global__ void __launch_bounds__(320) k_mix_out(const float* __restrict__ uftO,
        const float* __restrict__ w1re, const float* __restrict__ w1im,
        const float* __restrict__ w2re, const float* __restrict__ w2im,
        float* __restrict__ ffull) {
    int t = threadIdx.x; if (t >= 288) return;
    int o = blockIdx.x;
    int xm = t / 12, ky = t % 12;
    const float *wre, *wim; int xl;
    if (xm < 12) { wre = w1re; wim = w1im; xl = xm; }
    else         { wre = w2re; wim = w2im; xl = xm - 12; }
    float fr = 0.f, fi = 0.f;
    for (int i = 0; i < 64; ++i) {
        float2 u = *(const float2*)(uftO + ((size_t)i * 288 + t) * 2);
        int wi_ = ((i * 64 + o) * 12 + xl) * 12 + ky;
        float wr = wre[wi_], wq = wim[wi_];
        fr = fmaf(u.x, wr, fr); fr = fmaf(-u.y, wq, fr);
        fi = fmaf(u.x, wq, fi); fi = fmaf(u.y, wr, fi);
    }
    int M = xm * 23 + ky;
    ffull[((size_t)M * 64 + o) * 2]     = fr;
    ffull[((size_t)M * 64 + o) * 2 + 1] = fi;
    if (ky > 0) {
        int Mc = (23 - xm) * 23 + (23 - ky);
        ffull[((size_t)Mc * 64 + o) * 2]     = fr;
        ffull[((size_t)Mc * 64 + o) * 2 + 1] = -fi;
    }
}

// ---------------------------------------------------------------- project_out v6: LDS-staged ffull slice + e1 reg-cache
__global__ void __launch_bounds__(256, 4) k_proj_out(const float* __restrict__ ffull,
        const float* __restrict__ e1t, const float* __restrict__ e2t,
        float* __restrict__ uout) {
    __shared__ float4 sf[1104];   // 276 modes x (8 ch x re/im) = 4416 floats = 17.7 KB
    int t = threadIdx.x;
    int n = blockIdx.x * 256 + t;
    bool valid = n < G_N;
    int nn = valid ? n : 0;
    int c0 = blockIdx.y * 8;
    int x0 = blockIdx.z * 12;
    // stage ffull slice: modes M in [x0*23, x0*23+276), channels c0..c0+7 (16 floats each)
    {
        const float4* src = (const float4*)(ffull + ((size_t)(x0 * 23) * 64 + c0) * 2);
        // src rows are 32 float4 apart (64 ch * 2 / 4); we take 4 float4 per mode
        for (int i = t; i < 1104; i += 256) {
            int m = i >> 2, j = i & 3;
            sf[i] = src[(size_t)m * 32 + j];
        }
    }
    __syncthreads();
    const float2* E1 = (const float2*)e1t;
    const float2* E2 = (const float2*)e2t;
    float2 e1c[12];
    #pragma unroll
    for (int xi = 0; xi < 12; ++xi)
        e1c[xi] = E1[(size_t)(x0 + xi) * NPAD + nn];
    float acc[8];
    #pragma unroll
    for (int q = 0; q < 8; ++q) acc[q] = 0.f;
    for (int y = 0; y < 23; ++y) {
        float2 e2 = E2[(size_t)y * NPAD + nn];
        #pragma unroll
        for (int xi = 0; xi < 12; ++xi) {
            float2 e1 = e1c[xi];
            float br  =  e1.x * e2.x - e1.y * e2.y;
            float nbi = -(e1.x * e2.y + e1.y * e2.x);
            const float4* F = &sf[(xi * 23 + y) * 4];
            #pragma unroll
            for (int q = 0; q < 4; ++q) {
                float4 f = F[q];
                acc[q*2+0] = fmaf(f.x, br, acc[q*2+0]);
                acc[q*2+0] = fmaf(f.y, nbi, acc[q*2+0]);
                acc[q*2+1] = fmaf(f.z, br, acc[q*2+1]);
                acc[q*2+1] = fmaf(f.w, nbi, acc[q*2+1]);
            }
        }
    }
    if (valid) {
        float* ub = uout + (size_t)blockIdx.z * 1282048;
        #pragma unroll
        for (int q = 0; q < 8; ++q)
            ub[(size_t)(c0 + q) * NPAD + n] = acc[q];
    }
}

// ---------------------------------------------------------------- head MLP v2: 64 pts/block, 2-phase LDS (anti-spill)
__global__ void __launch_bounds__(256) k_head(const float* __restrict__ uout,
        const float* __restrict__ w1, const float* __restrict__ b1,
        const float* __restrict__ w2, const float* __restrict__ b2,
        float* __restrict__ out) {
    __shared__ float us[64][64];
    __shared__ float s_g[64][64];
    int t = threadIdx.x;
    int p = t & 63;
    int og = __builtin_amdgcn_readfirstlane(t >> 6);
    int nb = blockIdx.x * 64;
    for (int idx = t; idx < 4096; idx += 256) {
        int c = idx >> 6, pp = idx & 63;
        int n = nb + pp;
        int nn = (n < G_N) ? n : 0;
        us[c][pp] = uout[(size_t)c * NPAD + nn] + uout[1282048 + (size_t)c * NPAD + nn];
    }
    __syncthreads();
    #pragma unroll 2
    for (int i = 0; i < 16; ++i) {
        int o = og * 16 + i;
        float h = b1[o];
        for (int c = 0; c < 64; ++c) h = fmaf(us[c][p], w1[c * 64 + o], h);
        s_g[o][p] = gelu_exact(h);
    }
    __syncthreads();
    if (t < 192) {
        int oi = t >> 6;
        float v = b2[oi];
        for (int k = 0; k < 64; ++k) v = fmaf(s_g[k][p], w2[k * 3 + oi], v);
        int n = nb + p;
        if (n < G_N) out[(size_t)oi * G_N + n] = v;
    }
}

// ================================================================ launch
extern "C" void kernel_launch(void* const* d_in, const int* in_sizes, int n_in,
                              void* d_out, int out_size, void* d_ws, size_t ws_size,
                              hipStream_t stream) {
    const float* x        = (const float*)d_in[0];
    const float* coords   = (const float*)d_in[1];
    const float* pre_w1   = (const float*)d_in[2];
    const float* pre_b1   = (const float*)d_in[3];
    const float* pre_w2   = (const float*)d_in[4];
    const float* pre_b2   = (const float*)d_in[5];
    const float* pin_w1_re  = (const float*)d_in[6];
    const float* pin_w1_im  = (const float*)d_in[7];
    const float* pin_w2_re  = (const float*)d_in[8];
    const float* pin_w2_im  = (const float*)d_in[9];
    const float* pout_w1_re = (const float*)d_in[10];
    const float* pout_w1_im = (const float*)d_in[11];
    const float* pout_w2_re = (const float*)d_in[12];
    const float* pout_w2_im = (const float*)d_in[13];
    const float* ifc0w = (const float*)d_in[14];
    const float* ifc0b = (const float*)d_in[15];
    const float* ifncw = (const float*)d_in[16];
    const float* ifncb = (const float*)d_in[17];
    const float* ifc1w = (const float*)d_in[18];
    const float* ifc1b = (const float*)d_in[19];
    const float* ifc2w = (const float*)d_in[20];
    const float* ifc2b = (const float*)d_in[21];
    const float* ifc3w = (const float*)d_in[22];
    const float* ifc3b = (const float*)d_in[23];
    const float* ifc4w = (const float*)d_in[24];
    const float* ifc4b = (const float*)d_in[25];
    const float* wx_re = (const float*)d_in[26];
    const float* wx_im = (const float*)d_in[27];
    const float* wy_re = (const float*)d_in[28];
    const float* wy_im = (const float*)d_in[29];
    const float* hw1 = (const float*)d_in[30];
    const float* hb1 = (const float*)d_in[31];
    const float* hw2 = (const float*)d_in[32];
    const float* hb2 = (const float*)d_in[33];
    float* out = (float*)d_out;
    float* ws  = (float*)d_ws;

    float* ut      = ws + 0;          // [NPAD][64]
    float* ffull   = ws + 0;          // [552][64][2] (alias after ut dead)
    float* e1t     = ws + 1282048;    // [24][NPAD][2]
    float* e2t     = ws + 2243584;    // [23][NPAD][2]
    float* uft     = ws + 3165056;    // [64][288][2]  (later uftO)
    float* fmix    = ws + 3201920;    // [64][288][2]
    float* u       = ws + 3238784;    // [64][96][96]
    float* fy      = ws + 3828608;    // [64][12][96][2]
    float* fx      = ws + 3976064;
    float* gy      = ws + 4123520;
    float* gx      = ws + 4270976;
    float* partial = ws + 3238784;    // [125][36864] floats (alias, dead before u written)
    float* uout    = ws + 3238784;    // 2 x [64][NPAD] (alias after ogrid)

    k_pre<<<dim3(313), dim3(256), 0, stream>>>(x, coords, pre_w1, pre_b1, pre_w2, pre_b2, ut);
    k_iphi<<<dim3(625), dim3(256), 0, stream>>>(coords, ifc0w, ifc0b, ifncw, ifncb,
            ifc1w, ifc1b, ifc2w, ifc2b, ifc3w, ifc3b, ifc4w, ifc4b, e1t, e2t);
    k_proj_in<<<dim3(125, 8), dim3(320), 0, stream>>>(ut, e1t, e2t, partial);
    k_reduce<<<dim3(144), dim3(256), 0, stream>>>(partial, uft);
    k_mix_in<<<dim3(64), dim3(320), 0, stream>>>(uft, pin_w1_re, pin_w1_im, pin_w2_re, pin_w2_im, fmix);
    k_igrid<<<dim3(64, 4), dim3(256), 0, stream>>>(fmix, u);
    for (int L = 0; L < 4; ++L) {
        kf_dft<<<dim3(64, 4, 2), dim3(256), 0, stream>>>(u, fy, fx);
        kf_mix<<<dim3(64, 2, 3), dim3(384), 0, stream>>>(fy, fx,
                wy_re + (size_t)L * 49152, wy_im + (size_t)L * 49152,
                wx_re + (size_t)L * 49152, wx_im + (size_t)L * 49152, gy, gx);
        kf_inv<<<dim3(64, 4), dim3(256), 0, stream>>>(gy, gx, u);
    }
    k_ogrid<<<dim3(64), dim3(512), 0, stream>>>(u, uft /*as uftO*/);
    k_mix_out<<<dim3(64), dim3(320), 0, stream>>>(uft, pout_w1_re, pout_w1_im,
            pout_w2_re, pout_w2_im, ffull);
    k_proj_out<<<dim3(79, 8, 2), dim3(256), 0, stream>>>(ffull, e1t, e2t, uout);
    k_head<<<dim3(313), dim3(256), 0, stream>>>(uout, hw1, hb1, hw2, hb2, out);
}